// Round 12
// baseline (275.210 us; speedup 1.0000x reference)
//
#include <hip/hip_runtime.h>

// Problem constants
#define Bv 2
#define Hv 8
#define Lv 512
#define DKv 16
#define DMv 128          // H*DK
#define NKv 10
#define KSv 513

typedef __attribute__((ext_vector_type(8))) short short8;
typedef __attribute__((ext_vector_type(4))) float f32x4;

// chunk tables: nc_g = ceil((2^g+1)/16); chunks aligned to the END of the kernel
__device__ __constant__ int d_nc[10]     = {1,1,1,1,2,3,5,9,17,33};
__device__ __constant__ int d_cumnc[10]  = {0,1,2,3,4,6,9,14,23,40};
// total chunks = 73

// ws layout (bytes):
//   Y  : f32 [2 p][10 g][2 b][128 o][512 t]            = 10,485,760 B
//   xr : bf16 [2 p][2 b][512 t][128 i]                 =    524,288 B
//   Wb : bf16 [g][Tlocal][ A-frag layout ]             = 38,273,024 B
//        plane off(o,i) = ((o>>4)*4 + (i>>5))*512 + (o&15)*32 + (i&31)
#define Y_BYTES   (10485760)
#define XR_OFF    (Y_BYTES)
#define WB_OFF    (Y_BYTES + 524288)

__device__ inline unsigned short f2bf(float f) {
    unsigned u = __float_as_uint(f);
    unsigned r = (u + 0x7FFFu + ((u >> 16) & 1u)) >> 16;
    return (unsigned short)r;
}
__device__ inline float bf2f(short s) {
    return __uint_as_float(((unsigned)(unsigned short)s) << 16);
}

// ---------------------------------------------------------------------------
// prep: fused  (a) zero Y planes g4..g9 (both p)  (b) attn_out := 1.0
//              (c) repack_x  xr[p][b][t][i] = bf16(flat Q/K)
__global__ void prep(const float* __restrict__ Q, const float* __restrict__ K,
                     unsigned short* __restrict__ xr,
                     float4* __restrict__ Y4, float4* __restrict__ out4) {
    int stride = gridDim.x * 256;
    for (int i = blockIdx.x * 256 + threadIdx.x; i < 1507328; i += stride) {
        if (i < 196608) {
            Y4[131072 + i] = make_float4(0.f, 0.f, 0.f, 0.f);            // p0 g4..9
        } else if (i < 393216) {
            Y4[458752 + (i - 196608)] = make_float4(0.f, 0.f, 0.f, 0.f); // p1 g4..9
        } else if (i < 1441792) {
            out4[32768 + (i - 393216)] = make_float4(1.f, 1.f, 1.f, 1.f);
        } else {
            int idx = i - 1441792;               // 65536 items of 4 floats
            int flat = idx * 4;
            int p = flat >> 17;
            int off = flat & 131071;
            const float* src = p ? K : Q;
            float4 v = *(const float4*)(src + off);
            ushort4 o;
            o.x = f2bf(v.x); o.y = f2bf(v.y); o.z = f2bf(v.z); o.w = f2bf(v.w);
            *(ushort4*)(((unsigned short*)xr) + flat) = o;
        }
    }
}

// ---------------------------------------------------------------------------
// Wb plane layout: off(o,i) = ((o>>4)*4 + (i>>5))*512 + (o&15)*32 + (i&31)
__global__ __launch_bounds__(256) void repack_w(const float* __restrict__ W,
                                                unsigned short* __restrict__ wb) {
    int bid = blockIdx.x;
    int cid = bid >> 7;
    int o = bid & 127;
    int g, rem = cid;
#pragma unroll
    for (g = 0; g < 10; ++g) { int nc = d_nc[g]; if (rem < nc) break; rem -= nc; }
    int cl = rem;
    int w_g = d_nc[g] * 16;
    int ccol = w_g - 16 * (cl + 1);
    int wcolbase = 513 - w_g + ccol;      // absolute W col of this chunk's tap 0

    __shared__ float tile[128][17];       // [i][tap]
    const float* wsrc = W + (size_t)g * 16384 * 513 + (size_t)o * 128 * 513;
    int tid = threadIdx.x;
    int rr = tid >> 4, cc = tid & 15;
    int col = wcolbase + cc;
    for (int r = rr; r < 128; r += 16) {          // r = i
        float v = 0.f;
        if (col >= 0) v = wsrc[(size_t)r * 513 + col];
        tile[r][cc] = v;
    }
    __syncthreads();

    unsigned short* wdst = wb + (size_t)262144 * d_cumnc[g];
    int c2 = tid >> 4;          // tap 0..15
    int s  = tid & 15;          // ib(2) | qv(2)
    int ib = s >> 2, qv = s & 3;
    int i0 = ib * 32 + qv * 8;
    unsigned short pack[8];
#pragma unroll
    for (int e = 0; e < 8; ++e) pack[e] = f2bf(tile[i0 + e][c2]);
    size_t off = (size_t)(ccol + c2) * 16384 +
                 (((o >> 4) * 4 + ib) * 512 + (o & 15) * 32 + qv * 8);
    *(short8*)(wdst + off) = *(short8*)pack;      // 16B contiguous per thread
}

// ---------------------------------------------------------------------------
// conv v7: uniform per-chunk blocks, tile M=128 x N=256, 4 waves (2wm x 2wn).
// A-frags streamed L2->regs (coalesced 1KB wave-loads), no inner barriers.
// cid<=3 (g0..g3, sole writer) -> plain store; else atomic.
// Grid 640: j -> r=j&7 (XCD), yy=(j>>3)&7, cid=(j>>6)*8+r.
__global__ __launch_bounds__(256, 2) void conv_mfma(const unsigned short* __restrict__ xr,
                                                    const unsigned short* __restrict__ wb,
                                                    float* __restrict__ Y) {
    int j = blockIdx.x;
    int r = j & 7, yy = (j >> 3) & 7, qq = j >> 6;
    int cid = qq * 8 + r;
    if (cid >= 73) return;
    int g, rem = cid;
#pragma unroll
    for (g = 0; g < 10; ++g) { int nc = d_nc[g]; if (rem < nc) break; rem -= nc; }
    int cl = rem;
    int w_g = d_nc[g] * 16;
    int ccol = w_g - 16 * (cl + 1);

    int p = yy >> 2, b = (yy >> 1) & 1, tt = yy & 1;
    int t0 = tt * 256;
    int pb = yy >> 1;

    int xbase = t0 + 1 - 16 * (cl + 1);    // x index of xs row 0
    if (xbase < -270) return;              // read window entirely < 0

    // xs: element (u,i) at u*128 + (((i>>3)+u)&15)*8 + (i&7); 272 rows
    __shared__ unsigned short xs[272 * 128];

    int tid = threadIdx.x;
    const unsigned short* xp = xr + (size_t)pb * 65536;
    for (int e = tid; e < 272 * 16; e += 256) {
        int u = e >> 4, ic = e & 15;
        int xi = xbase + u;
        short8 v = (short8)0;
        if (xi >= 0 && xi < 512) v = *(const short8*)(xp + (size_t)xi * 128 + ic * 8);
        *(short8*)(&xs[u * 128 + (((ic + u) & 15) << 3)]) = v;
    }
    __syncthreads();                        // only barrier in the kernel

    int lane = tid & 63, wv = tid >> 6;     // 4 waves: 2 wm x 2 wn
    int wm = wv >> 1, wn = wv & 1;
    int l15 = lane & 15, q = lane >> 4;

    const unsigned short* wgp = wb + (size_t)262144 * d_cumnc[g] + (size_t)ccol * 16384;
    int abase = l15 * 32 + q * 8;

    f32x4 acc[4][8];
#pragma unroll
    for (int mt = 0; mt < 4; ++mt)
#pragma unroll
        for (int nt = 0; nt < 8; ++nt) acc[mt][nt] = (f32x4)0.f;

    for (int jj = 0; jj < 16; ++jj) {
        const unsigned short* tp = wgp + (size_t)jj * 16384;
        int row0 = wn * 128 + l15 + jj;
#pragma unroll
        for (int ib = 0; ib < 4; ++ib) {
            short8 a[4], bq[8];
#pragma unroll
            for (int mt = 0; mt < 4; ++mt)
                a[mt] = *(const short8*)(tp + ((wm * 4 + mt) * 4 + ib) * 512 + abase);
#pragma unroll
            for (int nt = 0; nt < 8; ++nt) {
                int row = row0 + nt * 16;
                bq[nt] = *(const short8*)(&xs[row * 128 + (((ib * 4 + q + row) & 15) << 3)]);
            }
#pragma unroll
            for (int mt = 0; mt < 4; ++mt)
#pragma unroll
                for (int nt = 0; nt < 8; ++nt)
                    acc[mt][nt] = __builtin_amdgcn_mfma_f32_16x16x32_bf16(
                        a[mt], bq[nt], acc[mt][nt], 0, 0, 0);
        }
    }

    // epilogue into Y[p][g][b][o][t]
    float* yp = Y + (((size_t)p * NKv + g) * 2 + b) * 65536;
    int orow = wm * 64 + q * 4;
    int tcol = t0 + wn * 128 + l15;
    if (cid <= 3) {
#pragma unroll
        for (int mt = 0; mt < 4; ++mt)
#pragma unroll
            for (int nt = 0; nt < 8; ++nt)
#pragma unroll
                for (int rr = 0; rr < 4; ++rr)
                    yp[(size_t)(orow + mt * 16 + rr) * 512 + tcol + nt * 16] =
                        acc[mt][nt][rr];
    } else {
#pragma unroll
        for (int mt = 0; mt < 4; ++mt)
#pragma unroll
            for (int nt = 0; nt < 8; ++nt)
#pragma unroll
                for (int rr = 0; rr < 4; ++rr)
                    atomicAdd(&yp[(size_t)(orow + mt * 16 + rr) * 512 + tcol + nt * 16],
                              acc[mt][nt][rr]);
    }
}

// ---------------------------------------------------------------------------
// Masked-entry context: ctx_masked[q,d] = 0.1 * sum_{k>q} S[k,d],
// S[k,d] = sum_g (K_p + bias). WRITES out ctx region.
__global__ __launch_bounds__(512) void suffix_ctx(const float* __restrict__ Y,
                                                  const float* __restrict__ bconv,
                                                  float* __restrict__ out) {
    int bh = blockIdx.x;        // 16
    int b = bh >> 3, h = bh & 7;
    int tid = threadIdx.x;
    int d = tid & 15;
    int s = tid >> 4;           // stripe 0..31, k in [s*16, s*16+16)

    __shared__ float tot[32][17];
    float S[16];
#pragma unroll
    for (int jv = 0; jv < 16; ++jv) {
        int k = s * 16 + jv;
        int o = h * 16 + (k >> 5);
        int t = (k & 31) * 16 + d;
        float acc = 0.f;
#pragma unroll
        for (int g = 0; g < NKv; ++g)
            acc += Y[(((size_t)(NKv + g) * 2 + b) * 65536) + (size_t)o * 512 + t]
                 + bconv[g * 128 + o];
        S[jv] = acc;
    }
    float mytot = 0.f;
#pragma unroll
    for (int jv = 0; jv < 16; ++jv) mytot += S[jv];
    tot[s][d] = mytot;
    __syncthreads();
    float run = 0.f;
    for (int s2 = s + 1; s2 < 32; ++s2) run += tot[s2][d];
#pragma unroll
    for (int jv = 15; jv >= 0; --jv) {
        int qv = s * 16 + jv;
        out[(((size_t)b * 8 + h) * 512 + qv) * 16 + d] = 0.1f * run;
        run += S[jv];
    }
}

// ---------------------------------------------------------------------------
// phase 2 via MFMA: per unit (32q x 32k), 4 waves each own a 16x16 subtile.
// Scores: 10x mfma_f32_16x16x32_bf16 (K=32, d 16..31 zero via broadcast
// zero-slot). C layout (conv-verified): k'=lane&15, q=(lane>>4)*4+r -> the
// g-softmax is lane-local, and each lane's 4 pairs share one k' so one bf16
// K-row read feeds 4 PV updates. Pair/quarter causal decomposition (r11).
// Masked pairs contribute 0 here (suffix_ctx owns the uniform-0.1 part).
// Grid 512 = 128 pairs x 4 quarters; 256 threads.
__global__ __launch_bounds__(256) void attn_mfma(const float* __restrict__ Y,
                                                 const float* __restrict__ bconv,
                                                 float* __restrict__ out) {
    int blk = blockIdx.x;
    int qr = blk & 3;
    int pr = blk >> 2;             // 128 pairs
    int bh = pr >> 3;
    int qp = pr & 7;
    int b = bh >> 3, h = bh & 7;

    int qtA = qp, qtB = 15 - qp;
    int u0 = qr * 4 + (qr ? 1 : 0);          // 0,5,9,13
    int u1 = u0 + (qr ? 4 : 5);              // 5,9,13,17

    // sh: Qs X=0 [0,7680) | Qs X=1 [7680,15360) | Ks [15360,23040) | zero [23040,23048)
    // row layout: [g*768 + row*24 + d], d=0..15 bf16
    __shared__ __align__(16) unsigned short sh[23048];

    int tid = threadIdx.x;
    int wv = tid >> 6, qh = wv >> 1, kh = wv & 1;
    int l = tid & 63, l15 = l & 15, lq = l >> 4;

    if (tid < 8) sh[23040 + tid] = 0;

    // stage Q tiles (both X) with bias
#pragma unroll
    for (int X = 0; X < 2; ++X) {
        int o = h * 16 + (X ? qtB : qtA);
        for (int e = tid; e < NKv * 128; e += 256) {
            int g = e >> 7, c = e & 127;
            float4 v = *(const float4*)(Y + (((size_t)g * 2 + b) * 65536) +
                                        (size_t)o * 512 + c * 4);
            float bb = bconv[g * 128 + o];
            ushort4 hh;
            hh.x = f2bf(v.x + bb); hh.y = f2bf(v.y + bb);
            hh.z = f2bf(v.z + bb); hh.w = f2bf(v.w + bb);
            *(ushort4*)&sh[X * 7680 + g * 768 + (c >> 2) * 24 + (c & 3) * 4] = hh;
        }
    }

    // per-lane fragment addresses (conv-verified A/B mapping; d>=16 -> zeros)
    int aoffq = (qh * 16 + l15) * 24 + lq * 8;           // valid when lq<2
    int boffk = (lq < 2) ? (15360 + (kh * 16 + l15) * 24 + lq * 8) : 23040;
    int astep = (lq < 2) ? 768 : 0;
    int kpv = 15360 + (kh * 16 + l15) * 24;              // PV K-row base (+g*768)

    float ctx[4][16];
#pragma unroll
    for (int r = 0; r < 4; ++r)
#pragma unroll
        for (int d = 0; d < 16; ++d) ctx[r][d] = 0.f;

    int curX = (u0 <= qtA) ? 0 : 1;
    int abase = (lq < 2) ? (curX * 7680 + aoffq) : 23040;

    for (int u = u0; u < u1; ++u) {
        int X = (u <= qtA) ? 0 : 1;
        int qt = X ? qtB : qtA;
        int kt = X ? (u - qtA - 1) : u;

        if (X != curX) {
            int pqt = curX ? qtB : qtA;
#pragma unroll
            for (int r = 0; r < 4; ++r)
#pragma unroll
                for (int d = 0; d < 16; ++d) {
                    float v = ctx[r][d];
                    v += __shfl_xor(v, 1);
                    v += __shfl_xor(v, 2);
                    v += __shfl_xor(v, 4);
                    v += __shfl_xor(v, 8);
                    if (l15 == 0)
                        atomicAdd(&out[(((size_t)b * 8 + h) * 512 + pqt * 32 +
                                        qh * 16 + lq * 4 + r) * 16 + d], v);
                    ctx[r][d] = 0.f;
                }
            curX = X;
            abase = (lq < 2) ? (X * 7680 + aoffq) : 23040;
        }

        __syncthreads();                      // prev-unit PV readers done
        int o_k = h * 16 + kt;
        for (int e = tid; e < NKv * 128; e += 256) {
            int g = e >> 7, c = e & 127;
            float4 v = *(const float4*)(Y + (((size_t)(NKv + g) * 2 + b) * 65536) +
                                        (size_t)o_k * 512 + c * 4);
            float bb = bconv[g * 128 + o_k];
            ushort4 hh;
            hh.x = f2bf(v.x + bb); hh.y = f2bf(v.y + bb);
            hh.z = f2bf(v.z + bb); hh.w = f2bf(v.w + bb);
            *(ushort4*)&sh[15360 + g * 768 + (c >> 2) * 24 + (c & 3) * 4] = hh;
        }
        __syncthreads();

        // scores: 10 independent MFMAs
        f32x4 z4 = (f32x4)0.f;
        f32x4 sg[10];
#pragma unroll
        for (int g = 0; g < NKv; ++g) {
            short8 af = *(const short8*)&sh[abase + g * astep];
            short8 bf = *(const short8*)&sh[boffk + g * astep];
            sg[g] = __builtin_amdgcn_mfma_f32_16x16x32_bf16(af, bf, z4, 0, 0, 0);
        }

        bool dg = (kt == qt);
        int kgl = kt * 32 + kh * 16 + l15;
        float wgt[10][4];
#pragma unroll
        for (int r = 0; r < 4; ++r) {
            int qgl = qt * 32 + qh * 16 + lq * 4 + r;
            float s0 = sg[0][r] * 0.25f;
            float mx = s0;
            float sv[10];
            sv[0] = s0;
#pragma unroll
            for (int g = 1; g < NKv; ++g) {
                sv[g] = sg[g][r] * 0.25f;
                mx = fmaxf(mx, sv[g]);
            }
            float sum = 0.f;
#pragma unroll
            for (int g = 0; g < NKv; ++g) {
                wgt[g][r] = __expf(sv[g] - mx);
                sum += wgt[g][r];
            }
            float inv = (dg && kgl > qgl) ? 0.f : (1.f / sum);
#pragma unroll
            for (int g = 0; g < NKv; ++g) wgt[g][r] *= inv;
        }

        // PV: one K-row read per g serves this lane's 4 pairs
#pragma unroll
        for (int g = 0; g < NKv; ++g) {
            short8 ka = *(const short8*)&sh[kpv + g * 768];
            short8 kb = *(const short8*)&sh[kpv + g * 768 + 8];
            float kvf[16];
#pragma unroll
            for (int jv = 0; jv < 8; ++jv) {
                kvf[jv]     = bf2f(ka[jv]);
                kvf[8 + jv] = bf2f(kb[jv]);
            }
#pragma unroll
            for (int r = 0; r < 4; ++r)
#pragma unroll
                for (int d = 0; d < 16; ++d)
                    ctx[r][d] = fmaf(wgt[g][r], kvf[d], ctx[r][d]);
        }
    }

    // final flush
    int pqt = curX ? qtB : qtA;
#pragma unroll
    for (int r = 0; r < 4; ++r)
#pragma unroll
        for (int d = 0; d < 16; ++d) {
            float v = ctx[r][d];
            v += __shfl_xor(v, 1);
            v += __shfl_xor(v, 2);
            v += __shfl_xor(v, 4);
            v += __shfl_xor(v, 8);
            if (l15 == 0)
                atomicAdd(&out[(((size_t)b * 8 + h) * 512 + pqt * 32 +
                                qh * 16 + lq * 4 + r) * 16 + d], v);
        }
}

// ---------------------------------------------------------------------------
extern "C" void kernel_launch(void* const* d_in, const int* in_sizes, int n_in,
                              void* d_out, int out_size, void* d_ws, size_t ws_size,
                              hipStream_t stream) {
    const float* Q = (const float*)d_in[0];
    const float* K = (const float*)d_in[1];
    const float* W = (const float*)d_in[3];
    const float* bconv = (const float*)d_in[4];
    float* out = (float*)d_out;

    float* Y = (float*)d_ws;
    unsigned short* xr = (unsigned short*)((char*)d_ws + XR_OFF);
    unsigned short* wb = (unsigned short*)((char*)d_ws + WB_OFF);

    prep<<<2048, 256, 0, stream>>>(Q, K, xr, (float4*)Y, (float4*)out);

    repack_w<<<73 * 128, 256, 0, stream>>>(W, wb);

    conv_mfma<<<640, 256, 0, stream>>>(xr, wb, Y);

    suffix_ctx<<<16, 512, 0, stream>>>(Y, bconv, out);

    attn_mfma<<<512, 256, 0, stream>>>(Y, bconv, out);
}

// Round 13
// 273.841 us; speedup vs baseline: 1.0050x; 1.0050x over previous
//
#include <hip/hip_runtime.h>

// Problem constants
#define Bv 2
#define Hv 8
#define Lv 512
#define DKv 16
#define DMv 128          // H*DK
#define NKv 10
#define KSv 513

typedef __attribute__((ext_vector_type(8))) short short8;
typedef __attribute__((ext_vector_type(4))) float f32x4;

// chunk tables: nc_g = ceil((2^g+1)/16); chunks aligned to the END of the kernel
__device__ __constant__ int d_nc[10]     = {1,1,1,1,2,3,5,9,17,33};
__device__ __constant__ int d_cumnc[10]  = {0,1,2,3,4,6,9,14,23,40};
// total chunks = 73

// ws layout (bytes):
//   Y  : f32 [2 p][10 g][2 b][128 o][512 t]            = 10,485,760 B
//   xr : bf16 [2 p][2 b][512 t][128 i]                 =    524,288 B
//   Wb : bf16 [g][Tlocal][ A-frag layout ]             = 38,273,024 B
//        plane off(o,i) = ((o>>4)*4 + (i>>5))*512 + (o&15)*32 + (i&31)
#define Y_BYTES   (10485760)
#define XR_OFF    (Y_BYTES)
#define WB_OFF    (Y_BYTES + 524288)

__device__ inline unsigned short f2bf(float f) {
    unsigned u = __float_as_uint(f);
    unsigned r = (u + 0x7FFFu + ((u >> 16) & 1u)) >> 16;
    return (unsigned short)r;
}

// ---------------------------------------------------------------------------
// prep: fused  (a) zero Y planes g4..g9 (both p)  (b) attn_out := 1.0
//              (c) repack_x  xr[p][b][t][i] = bf16(flat Q/K)
__global__ void prep(const float* __restrict__ Q, const float* __restrict__ K,
                     unsigned short* __restrict__ xr,
                     float4* __restrict__ Y4, float4* __restrict__ out4) {
    int stride = gridDim.x * 256;
    for (int i = blockIdx.x * 256 + threadIdx.x; i < 1507328; i += stride) {
        if (i < 196608) {
            Y4[131072 + i] = make_float4(0.f, 0.f, 0.f, 0.f);            // p0 g4..9
        } else if (i < 393216) {
            Y4[458752 + (i - 196608)] = make_float4(0.f, 0.f, 0.f, 0.f); // p1 g4..9
        } else if (i < 1441792) {
            out4[32768 + (i - 393216)] = make_float4(1.f, 1.f, 1.f, 1.f);
        } else {
            int idx = i - 1441792;               // 65536 items of 4 floats
            int flat = idx * 4;
            int p = flat >> 17;
            int off = flat & 131071;
            const float* src = p ? K : Q;
            float4 v = *(const float4*)(src + off);
            ushort4 o;
            o.x = f2bf(v.x); o.y = f2bf(v.y); o.z = f2bf(v.z); o.w = f2bf(v.w);
            *(ushort4*)(((unsigned short*)xr) + flat) = o;
        }
    }
}

// ---------------------------------------------------------------------------
// Wb plane layout: off(o,i) = ((o>>4)*4 + (i>>5))*512 + (o&15)*32 + (i&31)
__global__ __launch_bounds__(256) void repack_w(const float* __restrict__ W,
                                                unsigned short* __restrict__ wb) {
    int bid = blockIdx.x;
    int cid = bid >> 7;
    int o = bid & 127;
    int g, rem = cid;
#pragma unroll
    for (g = 0; g < 10; ++g) { int nc = d_nc[g]; if (rem < nc) break; rem -= nc; }
    int cl = rem;
    int w_g = d_nc[g] * 16;
    int ccol = w_g - 16 * (cl + 1);
    int wcolbase = 513 - w_g + ccol;      // absolute W col of this chunk's tap 0

    __shared__ float tile[128][17];       // [i][tap]
    const float* wsrc = W + (size_t)g * 16384 * 513 + (size_t)o * 128 * 513;
    int tid = threadIdx.x;
    int rr = tid >> 4, cc = tid & 15;
    int col = wcolbase + cc;
    for (int r = rr; r < 128; r += 16) {          // r = i
        float v = 0.f;
        if (col >= 0) v = wsrc[(size_t)r * 513 + col];
        tile[r][cc] = v;
    }
    __syncthreads();

    unsigned short* wdst = wb + (size_t)262144 * d_cumnc[g];
    int c2 = tid >> 4;          // tap 0..15
    int s  = tid & 15;          // ib(2) | qv(2)
    int ib = s >> 2, qv = s & 3;
    int i0 = ib * 32 + qv * 8;
    unsigned short pack[8];
#pragma unroll
    for (int e = 0; e < 8; ++e) pack[e] = f2bf(tile[i0 + e][c2]);
    size_t off = (size_t)(ccol + c2) * 16384 +
                 (((o >> 4) * 4 + ib) * 512 + (o & 15) * 32 + qv * 8);
    *(short8*)(wdst + off) = *(short8*)pack;      // 16B contiguous per thread
}

// ---------------------------------------------------------------------------
// conv v7: uniform per-chunk blocks, tile M=128 x N=256, 4 waves (2wm x 2wn).
// A-frags streamed L2->regs (coalesced 1KB wave-loads), no inner barriers.
// cid<=3 (g0..g3, sole writer) -> plain store; else atomic.
// Grid 640: j -> r=j&7 (XCD), yy=(j>>3)&7, cid=(j>>6)*8+r.
__global__ __launch_bounds__(256, 2) void conv_mfma(const unsigned short* __restrict__ xr,
                                                    const unsigned short* __restrict__ wb,
                                                    float* __restrict__ Y) {
    int j = blockIdx.x;
    int r = j & 7, yy = (j >> 3) & 7, qq = j >> 6;
    int cid = qq * 8 + r;
    if (cid >= 73) return;
    int g, rem = cid;
#pragma unroll
    for (g = 0; g < 10; ++g) { int nc = d_nc[g]; if (rem < nc) break; rem -= nc; }
    int cl = rem;
    int w_g = d_nc[g] * 16;
    int ccol = w_g - 16 * (cl + 1);

    int p = yy >> 2, b = (yy >> 1) & 1, tt = yy & 1;
    int t0 = tt * 256;
    int pb = yy >> 1;

    int xbase = t0 + 1 - 16 * (cl + 1);    // x index of xs row 0
    if (xbase < -270) return;              // read window entirely < 0

    // xs: element (u,i) at u*128 + (((i>>3)+u)&15)*8 + (i&7); 272 rows
    __shared__ unsigned short xs[272 * 128];

    int tid = threadIdx.x;
    const unsigned short* xp = xr + (size_t)pb * 65536;
    for (int e = tid; e < 272 * 16; e += 256) {
        int u = e >> 4, ic = e & 15;
        int xi = xbase + u;
        short8 v = (short8)0;
        if (xi >= 0 && xi < 512) v = *(const short8*)(xp + (size_t)xi * 128 + ic * 8);
        *(short8*)(&xs[u * 128 + (((ic + u) & 15) << 3)]) = v;
    }
    __syncthreads();                        // only barrier in the kernel

    int lane = tid & 63, wv = tid >> 6;     // 4 waves: 2 wm x 2 wn
    int wm = wv >> 1, wn = wv & 1;
    int l15 = lane & 15, q = lane >> 4;

    const unsigned short* wgp = wb + (size_t)262144 * d_cumnc[g] + (size_t)ccol * 16384;
    int abase = l15 * 32 + q * 8;

    f32x4 acc[4][8];
#pragma unroll
    for (int mt = 0; mt < 4; ++mt)
#pragma unroll
        for (int nt = 0; nt < 8; ++nt) acc[mt][nt] = (f32x4)0.f;

    for (int jj = 0; jj < 16; ++jj) {
        const unsigned short* tp = wgp + (size_t)jj * 16384;
        int row0 = wn * 128 + l15 + jj;
#pragma unroll
        for (int ib = 0; ib < 4; ++ib) {
            short8 a[4], bq[8];
#pragma unroll
            for (int mt = 0; mt < 4; ++mt)
                a[mt] = *(const short8*)(tp + ((wm * 4 + mt) * 4 + ib) * 512 + abase);
#pragma unroll
            for (int nt = 0; nt < 8; ++nt) {
                int row = row0 + nt * 16;
                bq[nt] = *(const short8*)(&xs[row * 128 + (((ib * 4 + q + row) & 15) << 3)]);
            }
#pragma unroll
            for (int mt = 0; mt < 4; ++mt)
#pragma unroll
                for (int nt = 0; nt < 8; ++nt)
                    acc[mt][nt] = __builtin_amdgcn_mfma_f32_16x16x32_bf16(
                        a[mt], bq[nt], acc[mt][nt], 0, 0, 0);
        }
    }

    // epilogue into Y[p][g][b][o][t]
    float* yp = Y + (((size_t)p * NKv + g) * 2 + b) * 65536;
    int orow = wm * 64 + q * 4;
    int tcol = t0 + wn * 128 + l15;
    if (cid <= 3) {
#pragma unroll
        for (int mt = 0; mt < 4; ++mt)
#pragma unroll
            for (int nt = 0; nt < 8; ++nt)
#pragma unroll
                for (int rr = 0; rr < 4; ++rr)
                    yp[(size_t)(orow + mt * 16 + rr) * 512 + tcol + nt * 16] =
                        acc[mt][nt][rr];
    } else {
#pragma unroll
        for (int mt = 0; mt < 4; ++mt)
#pragma unroll
            for (int nt = 0; nt < 8; ++nt)
#pragma unroll
                for (int rr = 0; rr < 4; ++rr)
                    atomicAdd(&yp[(size_t)(orow + mt * 16 + rr) * 512 + tcol + nt * 16],
                              acc[mt][nt][rr]);
    }
}

// ---------------------------------------------------------------------------
// Masked-entry context: ctx_masked[q,d] = 0.1 * sum_{k>q} S[k,d],
// S[k,d] = sum_g (K_p + bias). WRITES out ctx region.
__global__ __launch_bounds__(512) void suffix_ctx(const float* __restrict__ Y,
                                                  const float* __restrict__ bconv,
                                                  float* __restrict__ out) {
    int bh = blockIdx.x;        // 16
    int b = bh >> 3, h = bh & 7;
    int tid = threadIdx.x;
    int d = tid & 15;
    int s = tid >> 4;           // stripe 0..31, k in [s*16, s*16+16)

    __shared__ float tot[32][17];
    float S[16];
#pragma unroll
    for (int jv = 0; jv < 16; ++jv) {
        int k = s * 16 + jv;
        int o = h * 16 + (k >> 5);
        int t = (k & 31) * 16 + d;
        float acc = 0.f;
#pragma unroll
        for (int g = 0; g < NKv; ++g)
            acc += Y[(((size_t)(NKv + g) * 2 + b) * 65536) + (size_t)o * 512 + t]
                 + bconv[g * 128 + o];
        S[jv] = acc;
    }
    float mytot = 0.f;
#pragma unroll
    for (int jv = 0; jv < 16; ++jv) mytot += S[jv];
    tot[s][d] = mytot;
    __syncthreads();
    float run = 0.f;
    for (int s2 = s + 1; s2 < 32; ++s2) run += tot[s2][d];
#pragma unroll
    for (int jv = 15; jv >= 0; --jv) {
        int qv = s * 16 + jv;
        out[(((size_t)b * 8 + h) * 512 + qv) * 16 + d] = 0.1f * run;
        run += S[jv];
    }
}

// ---------------------------------------------------------------------------
// phase 2: unmasked (k<=q) part, online softmax over g. 1024 threads
// (32 q x 32 kl, no ki loop) -> 16 waves/block, 4 waves/SIMD for latency
// hiding of the dependent 16-FMA dot chains. Same math/layout as r11.
__global__ __launch_bounds__(1024) void attn_phase2(const float* __restrict__ Y,
                                                    const float* __restrict__ bconv,
                                                    float* __restrict__ out) {
    int blk = blockIdx.x;          // 256
    int half = blk & 1;
    int pr = blk >> 1;             // 128 pairs
    int bh = pr >> 3;
    int qp = pr & 7;
    int b = bh >> 3, h = bh & 7;

    int qtA = qp, qtB = 15 - qp;
    int u0 = half ? 8 : 0, u1 = half ? 17 : 8;

    __shared__ float Qs[2][NKv * 640];   // [X][g*640 + q*20 + d]
    __shared__ float Ks[NKv * 640];

    int tid = threadIdx.x;

#pragma unroll
    for (int X = 0; X < 2; ++X) {
        int o = h * 16 + (X ? qtB : qtA);
        for (int e = tid; e < NKv * 128; e += 1024) {
            int g = e >> 7, c = e & 127;
            float4 v = *(const float4*)(Y + (((size_t)g * 2 + b) * 65536) +
                                        (size_t)o * 512 + c * 4);
            float bb = bconv[g * 128 + o];
            int qq2 = c >> 2, dd = c & 3;
            *(float4*)&Qs[X][g * 640 + qq2 * 20 + dd * 4] =
                make_float4(v.x + bb, v.y + bb, v.z + bb, v.w + bb);
        }
    }

    int q = tid >> 5;    // 0..31
    int kl = tid & 31;   // 0..31
    float ctx[16];
#pragma unroll
    for (int d = 0; d < 16; ++d) ctx[d] = 0.f;
    int curX = (u0 <= qtA) ? 0 : 1;

    for (int u = u0; u < u1; ++u) {
        int X = (u <= qtA) ? 0 : 1;
        int qt = X ? qtB : qtA;
        int kt = X ? (u - qtA - 1) : u;

        if (X != curX) {
            int pqt = curX ? qtB : qtA;
#pragma unroll
            for (int d = 0; d < 16; ++d) {
                float v = ctx[d];
                v += __shfl_xor(v, 1);
                v += __shfl_xor(v, 2);
                v += __shfl_xor(v, 4);
                v += __shfl_xor(v, 8);
                v += __shfl_xor(v, 16);
                if (kl == 0)
                    atomicAdd(&out[(((size_t)b * 8 + h) * 512 + pqt * 32 + q) * 16 + d], v);
                ctx[d] = 0.f;
            }
            curX = X;
        }

        __syncthreads();
        int o_k = h * 16 + kt;
        for (int e = tid; e < NKv * 128; e += 1024) {
            int g = e >> 7, c = e & 127;
            float4 v = *(const float4*)(Y + (((size_t)(NKv + g) * 2 + b) * 65536) +
                                        (size_t)o_k * 512 + c * 4);
            float bb = bconv[g * 128 + o_k];
            int kk = c >> 2, dd = c & 3;
            *(float4*)&Ks[g * 640 + kk * 20 + dd * 4] =
                make_float4(v.x + bb, v.y + bb, v.z + bb, v.w + bb);
        }
        __syncthreads();

        int qg = qt * 32 + q;
        bool dg = (kt == qt);

        float m = -1e30f;
        float l = 0.f;
        float ca[16];
#pragma unroll
        for (int d = 0; d < 16; ++d) ca[d] = 0.f;

        for (int g = 0; g < NKv; ++g) {
            const float* Qg = &Qs[X][g * 640 + q * 20];
            float4 qv0 = *(const float4*)(Qg);
            float4 qv1 = *(const float4*)(Qg + 4);
            float4 qv2 = *(const float4*)(Qg + 8);
            float4 qv3 = *(const float4*)(Qg + 12);
            const float* Kg = &Ks[g * 640 + kl * 20];
            float kv[16];
            *(float4*)&kv[0]  = *(const float4*)(Kg);
            *(float4*)&kv[4]  = *(const float4*)(Kg + 4);
            *(float4*)&kv[8]  = *(const float4*)(Kg + 8);
            *(float4*)&kv[12] = *(const float4*)(Kg + 12);
            float s = 0.f;
            s = fmaf(qv0.x, kv[0], s);  s = fmaf(qv0.y, kv[1], s);
            s = fmaf(qv0.z, kv[2], s);  s = fmaf(qv0.w, kv[3], s);
            s = fmaf(qv1.x, kv[4], s);  s = fmaf(qv1.y, kv[5], s);
            s = fmaf(qv1.z, kv[6], s);  s = fmaf(qv1.w, kv[7], s);
            s = fmaf(qv2.x, kv[8], s);  s = fmaf(qv2.y, kv[9], s);
            s = fmaf(qv2.z, kv[10], s); s = fmaf(qv2.w, kv[11], s);
            s = fmaf(qv3.x, kv[12], s); s = fmaf(qv3.y, kv[13], s);
            s = fmaf(qv3.z, kv[14], s); s = fmaf(qv3.w, kv[15], s);
            s *= 0.25f;
            float mn = fmaxf(m, s);
            float sc = __expf(m - mn);
            float w  = __expf(s - mn);
            m = mn;
            l = l * sc + w;
#pragma unroll
            for (int d = 0; d < 16; ++d)
                ca[d] = fmaf(ca[d], sc, w * kv[d]);
        }

        int kg = kt * 32 + kl;
        float inv = (dg && kg > qg) ? 0.f : (1.f / l);
#pragma unroll
        for (int d = 0; d < 16; ++d) ctx[d] = fmaf(ca[d], inv, ctx[d]);
    }

    int pqt = curX ? qtB : qtA;
#pragma unroll
    for (int d = 0; d < 16; ++d) {
        float v = ctx[d];
        v += __shfl_xor(v, 1);
        v += __shfl_xor(v, 2);
        v += __shfl_xor(v, 4);
        v += __shfl_xor(v, 8);
        v += __shfl_xor(v, 16);
        if (kl == 0)
            atomicAdd(&out[(((size_t)b * 8 + h) * 512 + pqt * 32 + q) * 16 + d], v);
    }
}

// ---------------------------------------------------------------------------
extern "C" void kernel_launch(void* const* d_in, const int* in_sizes, int n_in,
                              void* d_out, int out_size, void* d_ws, size_t ws_size,
                              hipStream_t stream) {
    const float* Q = (const float*)d_in[0];
    const float* K = (const float*)d_in[1];
    const float* W = (const float*)d_in[3];
    const float* bconv = (const float*)d_in[4];
    float* out = (float*)d_out;

    float* Y = (float*)d_ws;
    unsigned short* xr = (unsigned short*)((char*)d_ws + XR_OFF);
    unsigned short* wb = (unsigned short*)((char*)d_ws + WB_OFF);

    prep<<<2048, 256, 0, stream>>>(Q, K, xr, (float4*)Y, (float4*)out);

    repack_w<<<73 * 128, 256, 0, stream>>>(W, wb);

    conv_mfma<<<640, 256, 0, stream>>>(xr, wb, Y);

    suffix_ctx<<<16, 512, 0, stream>>>(Y, bconv, out);

    attn_phase2<<<256, 1024, 0, stream>>>(Y, bconv, out);
}

// Round 14
// 259.369 us; speedup vs baseline: 1.0611x; 1.0558x over previous
//
#include <hip/hip_runtime.h>

// Problem constants
#define Bv 2
#define Hv 8
#define Lv 512
#define DKv 16
#define DMv 128          // H*DK
#define NKv 10
#define KSv 513

typedef __attribute__((ext_vector_type(8))) short short8;
typedef __attribute__((ext_vector_type(4))) float f32x4;

// chunk tables: nc_g = ceil((2^g+1)/16); chunks aligned to the END of the kernel
__device__ __constant__ int d_nc[10]     = {1,1,1,1,2,3,5,9,17,33};
__device__ __constant__ int d_cumnc[10]  = {0,1,2,3,4,6,9,14,23,40};
// total chunks = 73

// ws layout (bytes):
//   Y  : f32 [2 p][10 g][2 b][128 o][512 t]            = 10,485,760 B
//   xr : bf16 [2 p][2 b][512 t][128 i]                 =    524,288 B
//   Wb : bf16 [g][Tlocal][ A-frag layout ]             = 38,273,024 B
//        plane off(o,i) = ((o>>4)*4 + (i>>5))*512 + (o&15)*32 + (i&31)
#define Y_BYTES   (10485760)
#define XR_OFF    (Y_BYTES)
#define WB_OFF    (Y_BYTES + 524288)

__device__ inline unsigned short f2bf(float f) {
    unsigned u = __float_as_uint(f);
    unsigned r = (u + 0x7FFFu + ((u >> 16) & 1u)) >> 16;
    return (unsigned short)r;
}

// unpack 16 bf16 (two 16B-aligned b128 reads) -> 16 f32; 1 VALU op per value
__device__ __forceinline__ void unpk16(const unsigned short* p, float* f) {
    uint4 a = *(const uint4*)p;
    uint4 c = *(const uint4*)(p + 8);
    unsigned w;
    w = a.x; f[0]  = __uint_as_float(w << 16); f[1]  = __uint_as_float(w & 0xffff0000u);
    w = a.y; f[2]  = __uint_as_float(w << 16); f[3]  = __uint_as_float(w & 0xffff0000u);
    w = a.z; f[4]  = __uint_as_float(w << 16); f[5]  = __uint_as_float(w & 0xffff0000u);
    w = a.w; f[6]  = __uint_as_float(w << 16); f[7]  = __uint_as_float(w & 0xffff0000u);
    w = c.x; f[8]  = __uint_as_float(w << 16); f[9]  = __uint_as_float(w & 0xffff0000u);
    w = c.y; f[10] = __uint_as_float(w << 16); f[11] = __uint_as_float(w & 0xffff0000u);
    w = c.z; f[12] = __uint_as_float(w << 16); f[13] = __uint_as_float(w & 0xffff0000u);
    w = c.w; f[14] = __uint_as_float(w << 16); f[15] = __uint_as_float(w & 0xffff0000u);
}

// ---------------------------------------------------------------------------
// prep: fused  (a) zero Y planes g4..g9 (both p)  (b) attn_out := 1.0
//              (c) repack_x  xr[p][b][t][i] = bf16(flat Q/K)
__global__ void prep(const float* __restrict__ Q, const float* __restrict__ K,
                     unsigned short* __restrict__ xr,
                     float4* __restrict__ Y4, float4* __restrict__ out4) {
    int stride = gridDim.x * 256;
    for (int i = blockIdx.x * 256 + threadIdx.x; i < 1507328; i += stride) {
        if (i < 196608) {
            Y4[131072 + i] = make_float4(0.f, 0.f, 0.f, 0.f);            // p0 g4..9
        } else if (i < 393216) {
            Y4[458752 + (i - 196608)] = make_float4(0.f, 0.f, 0.f, 0.f); // p1 g4..9
        } else if (i < 1441792) {
            out4[32768 + (i - 393216)] = make_float4(1.f, 1.f, 1.f, 1.f);
        } else {
            int idx = i - 1441792;               // 65536 items of 4 floats
            int flat = idx * 4;
            int p = flat >> 17;
            int off = flat & 131071;
            const float* src = p ? K : Q;
            float4 v = *(const float4*)(src + off);
            ushort4 o;
            o.x = f2bf(v.x); o.y = f2bf(v.y); o.z = f2bf(v.z); o.w = f2bf(v.w);
            *(ushort4*)(((unsigned short*)xr) + flat) = o;
        }
    }
}

// ---------------------------------------------------------------------------
// Wb plane layout: off(o,i) = ((o>>4)*4 + (i>>5))*512 + (o&15)*32 + (i&31)
__global__ __launch_bounds__(256) void repack_w(const float* __restrict__ W,
                                                unsigned short* __restrict__ wb) {
    int bid = blockIdx.x;
    int cid = bid >> 7;
    int o = bid & 127;
    int g, rem = cid;
#pragma unroll
    for (g = 0; g < 10; ++g) { int nc = d_nc[g]; if (rem < nc) break; rem -= nc; }
    int cl = rem;
    int w_g = d_nc[g] * 16;
    int ccol = w_g - 16 * (cl + 1);
    int wcolbase = 513 - w_g + ccol;      // absolute W col of this chunk's tap 0

    __shared__ float tile[128][17];       // [i][tap]
    const float* wsrc = W + (size_t)g * 16384 * 513 + (size_t)o * 128 * 513;
    int tid = threadIdx.x;
    int rr = tid >> 4, cc = tid & 15;
    int col = wcolbase + cc;
    for (int r = rr; r < 128; r += 16) {          // r = i
        float v = 0.f;
        if (col >= 0) v = wsrc[(size_t)r * 513 + col];
        tile[r][cc] = v;
    }
    __syncthreads();

    unsigned short* wdst = wb + (size_t)262144 * d_cumnc[g];
    int c2 = tid >> 4;          // tap 0..15
    int s  = tid & 15;          // ib(2) | qv(2)
    int ib = s >> 2, qv = s & 3;
    int i0 = ib * 32 + qv * 8;
    unsigned short pack[8];
#pragma unroll
    for (int e = 0; e < 8; ++e) pack[e] = f2bf(tile[i0 + e][c2]);
    size_t off = (size_t)(ccol + c2) * 16384 +
                 (((o >> 4) * 4 + ib) * 512 + (o & 15) * 32 + qv * 8);
    *(short8*)(wdst + off) = *(short8*)pack;      // 16B contiguous per thread
}

// ---------------------------------------------------------------------------
// conv v7: uniform per-chunk blocks, tile M=128 x N=256, 4 waves (2wm x 2wn).
// A-frags streamed L2->regs (coalesced 1KB wave-loads), no inner barriers.
// cid<=3 (g0..g3, sole writer) -> plain store; else atomic.
// Grid 640: j -> r=j&7 (XCD), yy=(j>>3)&7, cid=(j>>6)*8+r.
__global__ __launch_bounds__(256, 2) void conv_mfma(const unsigned short* __restrict__ xr,
                                                    const unsigned short* __restrict__ wb,
                                                    float* __restrict__ Y) {
    int j = blockIdx.x;
    int r = j & 7, yy = (j >> 3) & 7, qq = j >> 6;
    int cid = qq * 8 + r;
    if (cid >= 73) return;
    int g, rem = cid;
#pragma unroll
    for (g = 0; g < 10; ++g) { int nc = d_nc[g]; if (rem < nc) break; rem -= nc; }
    int cl = rem;
    int w_g = d_nc[g] * 16;
    int ccol = w_g - 16 * (cl + 1);

    int p = yy >> 2, b = (yy >> 1) & 1, tt = yy & 1;
    int t0 = tt * 256;
    int pb = yy >> 1;

    int xbase = t0 + 1 - 16 * (cl + 1);    // x index of xs row 0
    if (xbase < -270) return;              // read window entirely < 0

    // xs: element (u,i) at u*128 + (((i>>3)+u)&15)*8 + (i&7); 272 rows
    __shared__ unsigned short xs[272 * 128];

    int tid = threadIdx.x;
    const unsigned short* xp = xr + (size_t)pb * 65536;
    for (int e = tid; e < 272 * 16; e += 256) {
        int u = e >> 4, ic = e & 15;
        int xi = xbase + u;
        short8 v = (short8)0;
        if (xi >= 0 && xi < 512) v = *(const short8*)(xp + (size_t)xi * 128 + ic * 8);
        *(short8*)(&xs[u * 128 + (((ic + u) & 15) << 3)]) = v;
    }
    __syncthreads();                        // only barrier in the kernel

    int lane = tid & 63, wv = tid >> 6;     // 4 waves: 2 wm x 2 wn
    int wm = wv >> 1, wn = wv & 1;
    int l15 = lane & 15, q = lane >> 4;

    const unsigned short* wgp = wb + (size_t)262144 * d_cumnc[g] + (size_t)ccol * 16384;
    int abase = l15 * 32 + q * 8;

    f32x4 acc[4][8];
#pragma unroll
    for (int mt = 0; mt < 4; ++mt)
#pragma unroll
        for (int nt = 0; nt < 8; ++nt) acc[mt][nt] = (f32x4)0.f;

    for (int jj = 0; jj < 16; ++jj) {
        const unsigned short* tp = wgp + (size_t)jj * 16384;
        int row0 = wn * 128 + l15 + jj;
#pragma unroll
        for (int ib = 0; ib < 4; ++ib) {
            short8 a[4], bq[8];
#pragma unroll
            for (int mt = 0; mt < 4; ++mt)
                a[mt] = *(const short8*)(tp + ((wm * 4 + mt) * 4 + ib) * 512 + abase);
#pragma unroll
            for (int nt = 0; nt < 8; ++nt) {
                int row = row0 + nt * 16;
                bq[nt] = *(const short8*)(&xs[row * 128 + (((ib * 4 + q + row) & 15) << 3)]);
            }
#pragma unroll
            for (int mt = 0; mt < 4; ++mt)
#pragma unroll
                for (int nt = 0; nt < 8; ++nt)
                    acc[mt][nt] = __builtin_amdgcn_mfma_f32_16x16x32_bf16(
                        a[mt], bq[nt], acc[mt][nt], 0, 0, 0);
        }
    }

    // epilogue into Y[p][g][b][o][t]
    float* yp = Y + (((size_t)p * NKv + g) * 2 + b) * 65536;
    int orow = wm * 64 + q * 4;
    int tcol = t0 + wn * 128 + l15;
    if (cid <= 3) {
#pragma unroll
        for (int mt = 0; mt < 4; ++mt)
#pragma unroll
            for (int nt = 0; nt < 8; ++nt)
#pragma unroll
                for (int rr = 0; rr < 4; ++rr)
                    yp[(size_t)(orow + mt * 16 + rr) * 512 + tcol + nt * 16] =
                        acc[mt][nt][rr];
    } else {
#pragma unroll
        for (int mt = 0; mt < 4; ++mt)
#pragma unroll
            for (int nt = 0; nt < 8; ++nt)
#pragma unroll
                for (int rr = 0; rr < 4; ++rr)
                    atomicAdd(&yp[(size_t)(orow + mt * 16 + rr) * 512 + tcol + nt * 16],
                              acc[mt][nt][rr]);
    }
}

// ---------------------------------------------------------------------------
// Masked-entry context: ctx_masked[q,d] = 0.1 * sum_{k>q} S[k,d],
// S[k,d] = sum_g (K_p + bias). WRITES out ctx region.
__global__ __launch_bounds__(512) void suffix_ctx(const float* __restrict__ Y,
                                                  const float* __restrict__ bconv,
                                                  float* __restrict__ out) {
    int bh = blockIdx.x;        // 16
    int b = bh >> 3, h = bh & 7;
    int tid = threadIdx.x;
    int d = tid & 15;
    int s = tid >> 4;           // stripe 0..31, k in [s*16, s*16+16)

    __shared__ float tot[32][17];
    float S[16];
#pragma unroll
    for (int jv = 0; jv < 16; ++jv) {
        int k = s * 16 + jv;
        int o = h * 16 + (k >> 5);
        int t = (k & 31) * 16 + d;
        float acc = 0.f;
#pragma unroll
        for (int g = 0; g < NKv; ++g)
            acc += Y[(((size_t)(NKv + g) * 2 + b) * 65536) + (size_t)o * 512 + t]
                 + bconv[g * 128 + o];
        S[jv] = acc;
    }
    float mytot = 0.f;
#pragma unroll
    for (int jv = 0; jv < 16; ++jv) mytot += S[jv];
    tot[s][d] = mytot;
    __syncthreads();
    float run = 0.f;
    for (int s2 = s + 1; s2 < 32; ++s2) run += tot[s2][d];
#pragma unroll
    for (int jv = 15; jv >= 0; --jv) {
        int qv = s * 16 + jv;
        out[(((size_t)b * 8 + h) * 512 + qv) * 16 + d] = 0.1f * run;
        run += S[jv];
    }
}

// ---------------------------------------------------------------------------
// phase 2: r11 structure (512 thr: 32 q x 16 kl, ki=2), online softmax over g,
// f32 math; Q_p/K_p staged in LDS as bf16 rows (16 bf16, stride 24 ushorts =
// 48B -> 16B-aligned b128, 2-way bank aliasing = free). Halves DS-pipe insts.
__global__ __launch_bounds__(512) void attn_phase2(const float* __restrict__ Y,
                                                   const float* __restrict__ bconv,
                                                   float* __restrict__ out) {
    int blk = blockIdx.x;          // 256
    int half = blk & 1;
    int pr = blk >> 1;             // 128 pairs
    int bh = pr >> 3;
    int qp = pr & 7;
    int b = bh >> 3, h = bh & 7;

    int qtA = qp, qtB = 15 - qp;
    int u0 = half ? 8 : 0, u1 = half ? 17 : 8;

    __shared__ __align__(16) unsigned short Qs[2][NKv * 768];  // [X][g*768+row*24+d]
    __shared__ __align__(16) unsigned short Ks[NKv * 768];

    int tid = threadIdx.x;

#pragma unroll
    for (int X = 0; X < 2; ++X) {
        int o = h * 16 + (X ? qtB : qtA);
        for (int e = tid; e < NKv * 128; e += 512) {
            int g = e >> 7, c = e & 127;
            float4 v = *(const float4*)(Y + (((size_t)g * 2 + b) * 65536) +
                                        (size_t)o * 512 + c * 4);
            float bb = bconv[g * 128 + o];
            ushort4 hh;
            hh.x = f2bf(v.x + bb); hh.y = f2bf(v.y + bb);
            hh.z = f2bf(v.z + bb); hh.w = f2bf(v.w + bb);
            *(ushort4*)&Qs[X][g * 768 + (c >> 2) * 24 + (c & 3) * 4] = hh;
        }
    }

    int q = (tid >> 4) & 31;
    int kl = tid & 15;
    float ctx[16];
#pragma unroll
    for (int d = 0; d < 16; ++d) ctx[d] = 0.f;
    int curX = (u0 <= qtA) ? 0 : 1;

    for (int u = u0; u < u1; ++u) {
        int X = (u <= qtA) ? 0 : 1;
        int qt = X ? qtB : qtA;
        int kt = X ? (u - qtA - 1) : u;

        if (X != curX) {
            int pqt = curX ? qtB : qtA;
#pragma unroll
            for (int d = 0; d < 16; ++d) {
                float v = ctx[d];
                v += __shfl_xor(v, 1);
                v += __shfl_xor(v, 2);
                v += __shfl_xor(v, 4);
                v += __shfl_xor(v, 8);
                if (kl == 0)
                    atomicAdd(&out[(((size_t)b * 8 + h) * 512 + pqt * 32 + q) * 16 + d], v);
                ctx[d] = 0.f;
            }
            curX = X;
        }

        __syncthreads();
        int o_k = h * 16 + kt;
        for (int e = tid; e < NKv * 128; e += 512) {
            int g = e >> 7, c = e & 127;
            float4 v = *(const float4*)(Y + (((size_t)(NKv + g) * 2 + b) * 65536) +
                                        (size_t)o_k * 512 + c * 4);
            float bb = bconv[g * 128 + o_k];
            ushort4 hh;
            hh.x = f2bf(v.x + bb); hh.y = f2bf(v.y + bb);
            hh.z = f2bf(v.z + bb); hh.w = f2bf(v.w + bb);
            *(ushort4*)&Ks[g * 768 + (c >> 2) * 24 + (c & 3) * 4] = hh;
        }
        __syncthreads();

        int qg = qt * 32 + q;
        bool dg = (kt == qt);

        float m[2] = {-1e30f, -1e30f};
        float l[2] = {0.f, 0.f};
        float ca[2][16];
#pragma unroll
        for (int ki = 0; ki < 2; ++ki)
#pragma unroll
            for (int d = 0; d < 16; ++d) ca[ki][d] = 0.f;

        for (int g = 0; g < NKv; ++g) {
            float qv[16];
            unpk16(&Qs[X][g * 768 + q * 24], qv);
#pragma unroll
            for (int ki = 0; ki < 2; ++ki) {
                float kv[16];
                unpk16(&Ks[g * 768 + (ki * 16 + kl) * 24], kv);
                float s = 0.f;
#pragma unroll
                for (int d = 0; d < 16; ++d)
                    s = fmaf(qv[d], kv[d], s);
                s *= 0.25f;
                float mn = fmaxf(m[ki], s);
                float sc = __expf(m[ki] - mn);
                float w  = __expf(s - mn);
                m[ki] = mn;
                l[ki] = l[ki] * sc + w;
#pragma unroll
                for (int d = 0; d < 16; ++d)
                    ca[ki][d] = fmaf(ca[ki][d], sc, w * kv[d]);
            }
        }

#pragma unroll
        for (int ki = 0; ki < 2; ++ki) {
            int kg = kt * 32 + ki * 16 + kl;
            float inv = (dg && kg > qg) ? 0.f : (1.f / l[ki]);
#pragma unroll
            for (int d = 0; d < 16; ++d) ctx[d] = fmaf(ca[ki][d], inv, ctx[d]);
        }
    }

    int pqt = curX ? qtB : qtA;
#pragma unroll
    for (int d = 0; d < 16; ++d) {
        float v = ctx[d];
        v += __shfl_xor(v, 1);
        v += __shfl_xor(v, 2);
        v += __shfl_xor(v, 4);
        v += __shfl_xor(v, 8);
        if (kl == 0)
            atomicAdd(&out[(((size_t)b * 8 + h) * 512 + pqt * 32 + q) * 16 + d], v);
    }
}

// ---------------------------------------------------------------------------
extern "C" void kernel_launch(void* const* d_in, const int* in_sizes, int n_in,
                              void* d_out, int out_size, void* d_ws, size_t ws_size,
                              hipStream_t stream) {
    const float* Q = (const float*)d_in[0];
    const float* K = (const float*)d_in[1];
    const float* W = (const float*)d_in[3];
    const float* bconv = (const float*)d_in[4];
    float* out = (float*)d_out;

    float* Y = (float*)d_ws;
    unsigned short* xr = (unsigned short*)((char*)d_ws + XR_OFF);
    unsigned short* wb = (unsigned short*)((char*)d_ws + WB_OFF);

    prep<<<2048, 256, 0, stream>>>(Q, K, xr, (float4*)Y, (float4*)out);

    repack_w<<<73 * 128, 256, 0, stream>>>(W, wb);

    conv_mfma<<<640, 256, 0, stream>>>(xr, wb, Y);

    suffix_ctx<<<16, 512, 0, stream>>>(Y, bconv, out);

    attn_phase2<<<256, 512, 0, stream>>>(Y, bconv, out);
}

// Round 15
// 233.940 us; speedup vs baseline: 1.1764x; 1.1087x over previous
//
#include <hip/hip_runtime.h>

// Problem constants
#define Bv 2
#define Hv 8
#define Lv 512
#define DKv 16
#define DMv 128          // H*DK
#define NKv 10
#define KSv 513

typedef __attribute__((ext_vector_type(8))) short short8;
typedef __attribute__((ext_vector_type(4))) float f32x4;

// chunk tables: nc_g = ceil((2^g+1)/16); chunks aligned to the END of the kernel
__device__ __constant__ int d_nc[10]     = {1,1,1,1,2,3,5,9,17,33};
__device__ __constant__ int d_cumnc[10]  = {0,1,2,3,4,6,9,14,23,40};
// total chunks = 73

// ws layout (bytes):
//   Y  : f32 [2 p][10 g][2 b][128 o][512 t]            = 10,485,760 B
//   xr : bf16 [2 p][2 b][512 t][128 i]                 =    524,288 B
//   Wb : bf16 [g][Tlocal][ A-frag layout ]             = 38,273,024 B
//        plane off(o,i) = ((o>>4)*4 + (i>>5))*512 + (o&15)*32 + (i&31)
#define Y_BYTES   (10485760)
#define XR_OFF    (Y_BYTES)
#define WB_OFF    (Y_BYTES + 524288)

__device__ inline unsigned short f2bf(float f) {
    unsigned u = __float_as_uint(f);
    unsigned r = (u + 0x7FFFu + ((u >> 16) & 1u)) >> 16;
    return (unsigned short)r;
}

// ---------------------------------------------------------------------------
// fused prep + repack_w (independent work, one launch):
//   blocks [0,9344): repack_w  — Wb[g][tap][Afrag(o,i)] <- bf16(W), 0-pad
//   blocks [9344,11392): prep  — zero Y g4..9, ones attn_out, repack_x
__global__ __launch_bounds__(256) void prep_repack(const float* __restrict__ Q,
                                                   const float* __restrict__ K,
                                                   const float* __restrict__ W,
                                                   unsigned short* __restrict__ xr,
                                                   unsigned short* __restrict__ wb,
                                                   float4* __restrict__ Y4,
                                                   float4* __restrict__ out4) {
    __shared__ float tile[128][17];       // [i][tap] (repack part only)
    int bid0 = blockIdx.x;
    int tid = threadIdx.x;

    if (bid0 < 9344) {
        int cid = bid0 >> 7;
        int o = bid0 & 127;
        int g, rem = cid;
#pragma unroll
        for (g = 0; g < 10; ++g) { int nc = d_nc[g]; if (rem < nc) break; rem -= nc; }
        int cl = rem;
        int w_g = d_nc[g] * 16;
        int ccol = w_g - 16 * (cl + 1);
        int wcolbase = 513 - w_g + ccol;      // absolute W col of chunk's tap 0

        const float* wsrc = W + (size_t)g * 16384 * 513 + (size_t)o * 128 * 513;
        int rr = tid >> 4, cc = tid & 15;
        int col = wcolbase + cc;
        for (int r = rr; r < 128; r += 16) {          // r = i
            float v = 0.f;
            if (col >= 0) v = wsrc[(size_t)r * 513 + col];
            tile[r][cc] = v;
        }
        __syncthreads();

        unsigned short* wdst = wb + (size_t)262144 * d_cumnc[g];
        int c2 = tid >> 4;          // tap 0..15
        int s  = tid & 15;          // ib(2) | qv(2)
        int ib = s >> 2, qv = s & 3;
        int i0 = ib * 32 + qv * 8;
        unsigned short pack[8];
#pragma unroll
        for (int e = 0; e < 8; ++e) pack[e] = f2bf(tile[i0 + e][c2]);
        size_t off = (size_t)(ccol + c2) * 16384 +
                     (((o >> 4) * 4 + ib) * 512 + (o & 15) * 32 + qv * 8);
        *(short8*)(wdst + off) = *(short8*)pack;      // 16B contiguous per thread
    } else {
        int stride = 2048 * 256;
        for (int i = (bid0 - 9344) * 256 + tid; i < 1507328; i += stride) {
            if (i < 196608) {
                Y4[131072 + i] = make_float4(0.f, 0.f, 0.f, 0.f);            // p0 g4..9
            } else if (i < 393216) {
                Y4[458752 + (i - 196608)] = make_float4(0.f, 0.f, 0.f, 0.f); // p1 g4..9
            } else if (i < 1441792) {
                out4[32768 + (i - 393216)] = make_float4(1.f, 1.f, 1.f, 1.f);
            } else {
                int idx = i - 1441792;               // 65536 items of 4 floats
                int flat = idx * 4;
                int p = flat >> 17;
                int off = flat & 131071;
                const float* src = p ? K : Q;
                float4 v = *(const float4*)(src + off);
                ushort4 o4;
                o4.x = f2bf(v.x); o4.y = f2bf(v.y); o4.z = f2bf(v.z); o4.w = f2bf(v.w);
                *(ushort4*)(xr + flat) = o4;
            }
        }
    }
}

// ---------------------------------------------------------------------------
// conv v7: uniform per-chunk blocks, tile M=128 x N=256, 4 waves (2wm x 2wn).
// A-frags streamed L2->regs (coalesced 1KB wave-loads), no inner barriers.
// cid<=3 (g0..g3, sole writer) -> plain store; else atomic.
// Grid 640: j -> r=j&7 (XCD), yy=(j>>3)&7, cid=(j>>6)*8+r.
__global__ __launch_bounds__(256, 2) void conv_mfma(const unsigned short* __restrict__ xr,
                                                    const unsigned short* __restrict__ wb,
                                                    float* __restrict__ Y) {
    int j = blockIdx.x;
    int r = j & 7, yy = (j >> 3) & 7, qq = j >> 6;
    int cid = qq * 8 + r;
    if (cid >= 73) return;
    int g, rem = cid;
#pragma unroll
    for (g = 0; g < 10; ++g) { int nc = d_nc[g]; if (rem < nc) break; rem -= nc; }
    int cl = rem;
    int w_g = d_nc[g] * 16;
    int ccol = w_g - 16 * (cl + 1);

    int p = yy >> 2, b = (yy >> 1) & 1, tt = yy & 1;
    int t0 = tt * 256;
    int pb = yy >> 1;

    int xbase = t0 + 1 - 16 * (cl + 1);    // x index of xs row 0
    if (xbase < -270) return;              // read window entirely < 0

    // xs: element (u,i) at u*128 + (((i>>3)+u)&15)*8 + (i&7); 272 rows
    __shared__ unsigned short xs[272 * 128];

    int tid = threadIdx.x;
    const unsigned short* xp = xr + (size_t)pb * 65536;
    for (int e = tid; e < 272 * 16; e += 256) {
        int u = e >> 4, ic = e & 15;
        int xi = xbase + u;
        short8 v = (short8)0;
        if (xi >= 0 && xi < 512) v = *(const short8*)(xp + (size_t)xi * 128 + ic * 8);
        *(short8*)(&xs[u * 128 + (((ic + u) & 15) << 3)]) = v;
    }
    __syncthreads();                        // only barrier in the kernel

    int lane = tid & 63, wv = tid >> 6;     // 4 waves: 2 wm x 2 wn
    int wm = wv >> 1, wn = wv & 1;
    int l15 = lane & 15, q = lane >> 4;

    const unsigned short* wgp = wb + (size_t)262144 * d_cumnc[g] + (size_t)ccol * 16384;
    int abase = l15 * 32 + q * 8;

    f32x4 acc[4][8];
#pragma unroll
    for (int mt = 0; mt < 4; ++mt)
#pragma unroll
        for (int nt = 0; nt < 8; ++nt) acc[mt][nt] = (f32x4)0.f;

    for (int jj = 0; jj < 16; ++jj) {
        const unsigned short* tp = wgp + (size_t)jj * 16384;
        int row0 = wn * 128 + l15 + jj;
#pragma unroll
        for (int ib = 0; ib < 4; ++ib) {
            short8 a[4], bq[8];
#pragma unroll
            for (int mt = 0; mt < 4; ++mt)
                a[mt] = *(const short8*)(tp + ((wm * 4 + mt) * 4 + ib) * 512 + abase);
#pragma unroll
            for (int nt = 0; nt < 8; ++nt) {
                int row = row0 + nt * 16;
                bq[nt] = *(const short8*)(&xs[row * 128 + (((ib * 4 + q + row) & 15) << 3)]);
            }
#pragma unroll
            for (int mt = 0; mt < 4; ++mt)
#pragma unroll
                for (int nt = 0; nt < 8; ++nt)
                    acc[mt][nt] = __builtin_amdgcn_mfma_f32_16x16x32_bf16(
                        a[mt], bq[nt], acc[mt][nt], 0, 0, 0);
        }
    }

    // epilogue into Y[p][g][b][o][t]
    float* yp = Y + (((size_t)p * NKv + g) * 2 + b) * 65536;
    int orow = wm * 64 + q * 4;
    int tcol = t0 + wn * 128 + l15;
    if (cid <= 3) {
#pragma unroll
        for (int mt = 0; mt < 4; ++mt)
#pragma unroll
            for (int nt = 0; nt < 8; ++nt)
#pragma unroll
                for (int rr = 0; rr < 4; ++rr)
                    yp[(size_t)(orow + mt * 16 + rr) * 512 + tcol + nt * 16] =
                        acc[mt][nt][rr];
    } else {
#pragma unroll
        for (int mt = 0; mt < 4; ++mt)
#pragma unroll
            for (int nt = 0; nt < 8; ++nt)
#pragma unroll
                for (int rr = 0; rr < 4; ++rr)
                    atomicAdd(&yp[(size_t)(orow + mt * 16 + rr) * 512 + tcol + nt * 16],
                              acc[mt][nt][rr]);
    }
}

// ---------------------------------------------------------------------------
// Masked-entry context, parallel v2: grid 256 = (bh x d-column). Each block:
// thread k computes S[k] = sum_g(K_p+bias), 9-step Hillis-Steele suffix scan
// in LDS, write ctx_masked[q,d] = 0.1 * sum_{k>q} S[k].
__global__ __launch_bounds__(512) void suffix_ctx(const float* __restrict__ Y,
                                                  const float* __restrict__ bconv,
                                                  float* __restrict__ out) {
    int blk = blockIdx.x;           // 256 = bh*16 + d
    int bh = blk >> 4, d = blk & 15;
    int b = bh >> 3, h = bh & 7;
    int k = threadIdx.x;            // 0..511
    int o = h * 16 + (k >> 5);
    int t = (k & 31) * 16 + d;

    float S = 0.f;
#pragma unroll
    for (int g = 0; g < NKv; ++g)
        S += Y[(((size_t)(NKv + g) * 2 + b) * 65536) + (size_t)o * 512 + t]
           + bconv[g * 128 + o];

    __shared__ float sc[512];
    sc[k] = S;
    __syncthreads();
    float v = S;
    for (int ofs = 1; ofs < 512; ofs <<= 1) {
        float add = (k + ofs < 512) ? sc[k + ofs] : 0.f;
        __syncthreads();
        v += add;
        sc[k] = v;
        __syncthreads();
    }
    // v = inclusive suffix sum; exclusive = v - S
    out[(((size_t)b * 8 + h) * 512 + k) * 16 + d] = 0.1f * (v - S);
}

// ---------------------------------------------------------------------------
// phase 2 (r11-verified f32 version): unmasked (k<=q) part, online softmax
// over g, 512 threads (32 q x 16 kl, 2 ki) -> 2 waves/SIMD.
__global__ __launch_bounds__(512) void attn_phase2(const float* __restrict__ Y,
                                                   const float* __restrict__ bconv,
                                                   float* __restrict__ out) {
    int blk = blockIdx.x;          // 256
    int half = blk & 1;
    int pr = blk >> 1;             // 128 pairs
    int bh = pr >> 3;
    int qp = pr & 7;
    int b = bh >> 3, h = bh & 7;

    int qtA = qp, qtB = 15 - qp;
    int u0 = half ? 8 : 0, u1 = half ? 17 : 8;

    __shared__ float Qs[2][NKv * 640];   // [X][g*640 + q*20 + d]
    __shared__ float Ks[NKv * 640];

    int tid = threadIdx.x;

#pragma unroll
    for (int X = 0; X < 2; ++X) {
        int o = h * 16 + (X ? qtB : qtA);
        for (int e = tid; e < NKv * 128; e += 512) {
            int g = e >> 7, c = e & 127;
            float4 v = *(const float4*)(Y + (((size_t)g * 2 + b) * 65536) +
                                        (size_t)o * 512 + c * 4);
            float bb = bconv[g * 128 + o];
            int qq2 = c >> 2, dd = c & 3;
            *(float4*)&Qs[X][g * 640 + qq2 * 20 + dd * 4] =
                make_float4(v.x + bb, v.y + bb, v.z + bb, v.w + bb);
        }
    }

    int q = (tid >> 4) & 31;
    int kl = tid & 15;
    float ctx[16];
#pragma unroll
    for (int d = 0; d < 16; ++d) ctx[d] = 0.f;
    int curX = (u0 <= qtA) ? 0 : 1;

    for (int u = u0; u < u1; ++u) {
        int X = (u <= qtA) ? 0 : 1;
        int qt = X ? qtB : qtA;
        int kt = X ? (u - qtA - 1) : u;

        if (X != curX) {
            int pqt = curX ? qtB : qtA;
#pragma unroll
            for (int d = 0; d < 16; ++d) {
                float v = ctx[d];
                v += __shfl_xor(v, 1);
                v += __shfl_xor(v, 2);
                v += __shfl_xor(v, 4);
                v += __shfl_xor(v, 8);
                if (kl == 0)
                    atomicAdd(&out[(((size_t)b * 8 + h) * 512 + pqt * 32 + q) * 16 + d], v);
                ctx[d] = 0.f;
            }
            curX = X;
        }

        __syncthreads();
        int o_k = h * 16 + kt;
        for (int e = tid; e < NKv * 128; e += 512) {
            int g = e >> 7, c = e & 127;
            float4 v = *(const float4*)(Y + (((size_t)(NKv + g) * 2 + b) * 65536) +
                                        (size_t)o_k * 512 + c * 4);
            float bb = bconv[g * 128 + o_k];
            int kk = c >> 2, dd = c & 3;
            *(float4*)&Ks[g * 640 + kk * 20 + dd * 4] =
                make_float4(v.x + bb, v.y + bb, v.z + bb, v.w + bb);
        }
        __syncthreads();

        int qg = qt * 32 + q;
        bool dg = (kt == qt);

        float m[2] = {-1e30f, -1e30f};
        float l[2] = {0.f, 0.f};
        float ca[2][16];
#pragma unroll
        for (int ki = 0; ki < 2; ++ki)
#pragma unroll
            for (int d = 0; d < 16; ++d) ca[ki][d] = 0.f;

        for (int g = 0; g < NKv; ++g) {
            const float* Qg = &Qs[X][g * 640 + q * 20];
            float4 qv0 = *(const float4*)(Qg);
            float4 qv1 = *(const float4*)(Qg + 4);
            float4 qv2 = *(const float4*)(Qg + 8);
            float4 qv3 = *(const float4*)(Qg + 12);
#pragma unroll
            for (int ki = 0; ki < 2; ++ki) {
                const float* Kg = &Ks[g * 640 + (ki * 16 + kl) * 20];
                float kv[16];
                *(float4*)&kv[0]  = *(const float4*)(Kg);
                *(float4*)&kv[4]  = *(const float4*)(Kg + 4);
                *(float4*)&kv[8]  = *(const float4*)(Kg + 8);
                *(float4*)&kv[12] = *(const float4*)(Kg + 12);
                float s = 0.f;
                s = fmaf(qv0.x, kv[0], s);  s = fmaf(qv0.y, kv[1], s);
                s = fmaf(qv0.z, kv[2], s);  s = fmaf(qv0.w, kv[3], s);
                s = fmaf(qv1.x, kv[4], s);  s = fmaf(qv1.y, kv[5], s);
                s = fmaf(qv1.z, kv[6], s);  s = fmaf(qv1.w, kv[7], s);
                s = fmaf(qv2.x, kv[8], s);  s = fmaf(qv2.y, kv[9], s);
                s = fmaf(qv2.z, kv[10], s); s = fmaf(qv2.w, kv[11], s);
                s = fmaf(qv3.x, kv[12], s); s = fmaf(qv3.y, kv[13], s);
                s = fmaf(qv3.z, kv[14], s); s = fmaf(qv3.w, kv[15], s);
                s *= 0.25f;
                float mn = fmaxf(m[ki], s);
                float sc = __expf(m[ki] - mn);
                float w  = __expf(s - mn);
                m[ki] = mn;
                l[ki] = l[ki] * sc + w;
#pragma unroll
                for (int d = 0; d < 16; ++d)
                    ca[ki][d] = fmaf(ca[ki][d], sc, w * kv[d]);
            }
        }

#pragma unroll
        for (int ki = 0; ki < 2; ++ki) {
            int kg = kt * 32 + ki * 16 + kl;
            float inv = (dg && kg > qg) ? 0.f : (1.f / l[ki]);
#pragma unroll
            for (int d = 0; d < 16; ++d) ctx[d] = fmaf(ca[ki][d], inv, ctx[d]);
        }
    }

    int pqt = curX ? qtB : qtA;
#pragma unroll
    for (int d = 0; d < 16; ++d) {
        float v = ctx[d];
        v += __shfl_xor(v, 1);
        v += __shfl_xor(v, 2);
        v += __shfl_xor(v, 4);
        v += __shfl_xor(v, 8);
        if (kl == 0)
            atomicAdd(&out[(((size_t)b * 8 + h) * 512 + pqt * 32 + q) * 16 + d], v);
    }
}

// ---------------------------------------------------------------------------
extern "C" void kernel_launch(void* const* d_in, const int* in_sizes, int n_in,
                              void* d_out, int out_size, void* d_ws, size_t ws_size,
                              hipStream_t stream) {
    const float* Q = (const float*)d_in[0];
    const float* K = (const float*)d_in[1];
    const float* W = (const float*)d_in[3];
    const float* bconv = (const float*)d_in[4];
    float* out = (float*)d_out;

    float* Y = (float*)d_ws;
    unsigned short* xr = (unsigned short*)((char*)d_ws + XR_OFF);
    unsigned short* wb = (unsigned short*)((char*)d_ws + WB_OFF);

    prep_repack<<<11392, 256, 0, stream>>>(Q, K, W, xr, wb, (float4*)Y, (float4*)out);

    conv_mfma<<<640, 256, 0, stream>>>(xr, wb, Y);

    suffix_ctx<<<256, 512, 0, stream>>>(Y, bconv, out);

    attn_phase2<<<256, 512, 0, stream>>>(Y, bconv, out);
}

// Round 16
// 199.315 us; speedup vs baseline: 1.3808x; 1.1737x over previous
//
#include <hip/hip_runtime.h>

// Problem constants
#define Bv 2
#define Hv 8
#define Lv 512
#define DKv 16
#define DMv 128          // H*DK
#define NKv 10
#define KSv 513

typedef __attribute__((ext_vector_type(8))) short short8;
typedef __attribute__((ext_vector_type(4))) float f32x4;

// chunk tables: nc_g = ceil((2^g+1)/16); chunks aligned to the END of the kernel
__device__ __constant__ int d_nc[10]     = {1,1,1,1,2,3,5,9,17,33};
__device__ __constant__ int d_cumnc[10]  = {0,1,2,3,4,6,9,14,23,40};
// total chunks = 73

// ws layout (bytes):
//   Y  : f32 [2 p][10 g][2 b][128 o][512 t]            = 10,485,760 B
//   xr : bf16 [2 p][2 b][512 t][128 i]                 =    524,288 B
//   Wb : bf16 [g][Tlocal][ A-frag layout ]             = 38,273,024 B
//        plane off(o,i) = ((o>>4)*4 + (i>>5))*512 + (o&15)*32 + (i&31)
#define Y_BYTES   (10485760)
#define XR_OFF    (Y_BYTES)
#define WB_OFF    (Y_BYTES + 524288)

__device__ inline unsigned short f2bf(float f) {
    unsigned u = __float_as_uint(f);
    unsigned r = (u + 0x7FFFu + ((u >> 16) & 1u)) >> 16;
    return (unsigned short)r;
}

// ---------------------------------------------------------------------------
// fused prep + repack_w (independent work, one launch):
//   blocks [0,9344): repack_w  — Wb[g][tap][Afrag(o,i)] <- bf16(W), 0-pad
//   blocks [9344,11392): prep  — zero Y g4..9, ones attn_out, repack_x
__global__ __launch_bounds__(256) void prep_repack(const float* __restrict__ Q,
                                                   const float* __restrict__ K,
                                                   const float* __restrict__ W,
                                                   unsigned short* __restrict__ xr,
                                                   unsigned short* __restrict__ wb,
                                                   float4* __restrict__ Y4,
                                                   float4* __restrict__ out4) {
    __shared__ float tile[128][17];       // [i][tap] (repack part only)
    int bid0 = blockIdx.x;
    int tid = threadIdx.x;

    if (bid0 < 9344) {
        int cid = bid0 >> 7;
        int o = bid0 & 127;
        int g, rem = cid;
#pragma unroll
        for (g = 0; g < 10; ++g) { int nc = d_nc[g]; if (rem < nc) break; rem -= nc; }
        int cl = rem;
        int w_g = d_nc[g] * 16;
        int ccol = w_g - 16 * (cl + 1);
        int wcolbase = 513 - w_g + ccol;      // absolute W col of chunk's tap 0

        const float* wsrc = W + (size_t)g * 16384 * 513 + (size_t)o * 128 * 513;
        int rr = tid >> 4, cc = tid & 15;
        int col = wcolbase + cc;
        for (int r = rr; r < 128; r += 16) {          // r = i
            float v = 0.f;
            if (col >= 0) v = wsrc[(size_t)r * 513 + col];
            tile[r][cc] = v;
        }
        __syncthreads();

        unsigned short* wdst = wb + (size_t)262144 * d_cumnc[g];
        int c2 = tid >> 4;          // tap 0..15
        int s  = tid & 15;          // ib(2) | qv(2)
        int ib = s >> 2, qv = s & 3;
        int i0 = ib * 32 + qv * 8;
        unsigned short pack[8];
#pragma unroll
        for (int e = 0; e < 8; ++e) pack[e] = f2bf(tile[i0 + e][c2]);
        size_t off = (size_t)(ccol + c2) * 16384 +
                     (((o >> 4) * 4 + ib) * 512 + (o & 15) * 32 + qv * 8);
        *(short8*)(wdst + off) = *(short8*)pack;      // 16B contiguous per thread
    } else {
        int stride = 2048 * 256;
        for (int i = (bid0 - 9344) * 256 + tid; i < 1507328; i += stride) {
            if (i < 196608) {
                Y4[131072 + i] = make_float4(0.f, 0.f, 0.f, 0.f);            // p0 g4..9
            } else if (i < 393216) {
                Y4[458752 + (i - 196608)] = make_float4(0.f, 0.f, 0.f, 0.f); // p1 g4..9
            } else if (i < 1441792) {
                out4[32768 + (i - 393216)] = make_float4(1.f, 1.f, 1.f, 1.f);
            } else {
                int idx = i - 1441792;               // 65536 items of 4 floats
                int flat = idx * 4;
                int p = flat >> 17;
                int off = flat & 131071;
                const float* src = p ? K : Q;
                float4 v = *(const float4*)(src + off);
                ushort4 o4;
                o4.x = f2bf(v.x); o4.y = f2bf(v.y); o4.z = f2bf(v.z); o4.w = f2bf(v.w);
                *(ushort4*)(xr + flat) = o4;
            }
        }
    }
}

// ---------------------------------------------------------------------------
// conv v8: v7 + explicit register ping-pong software pipeline. Flattened
// (tap,ib) loop of 64 steps; step k+1's 4 A-frags (global/L2, coalesced 1KB
// wave-loads) + 8 B-frags (LDS) prefetched while step k's 32 MFMAs run.
// cid<=3 (g0..g3, sole writer) -> plain store; else atomic.
// Grid 640: j -> r=j&7 (XCD), yy=(j>>3)&7, cid=(j>>6)*8+r.
__global__ __launch_bounds__(256, 2) void conv_mfma(const unsigned short* __restrict__ xr,
                                                    const unsigned short* __restrict__ wb,
                                                    float* __restrict__ Y) {
    int j = blockIdx.x;
    int r = j & 7, yy = (j >> 3) & 7, qq = j >> 6;
    int cid = qq * 8 + r;
    if (cid >= 73) return;
    int g, rem = cid;
#pragma unroll
    for (g = 0; g < 10; ++g) { int nc = d_nc[g]; if (rem < nc) break; rem -= nc; }
    int cl = rem;
    int w_g = d_nc[g] * 16;
    int ccol = w_g - 16 * (cl + 1);

    int p = yy >> 2, b = (yy >> 1) & 1, tt = yy & 1;
    int t0 = tt * 256;
    int pb = yy >> 1;

    int xbase = t0 + 1 - 16 * (cl + 1);    // x index of xs row 0
    if (xbase < -270) return;              // read window entirely < 0

    // xs: element (u,i) at u*128 + (((i>>3)+u)&15)*8 + (i&7); 272 rows
    __shared__ unsigned short xs[272 * 128];

    int tid = threadIdx.x;
    const unsigned short* xp = xr + (size_t)pb * 65536;
    for (int e = tid; e < 272 * 16; e += 256) {
        int u = e >> 4, ic = e & 15;
        int xi = xbase + u;
        short8 v = (short8)0;
        if (xi >= 0 && xi < 512) v = *(const short8*)(xp + (size_t)xi * 128 + ic * 8);
        *(short8*)(&xs[u * 128 + (((ic + u) & 15) << 3)]) = v;
    }
    __syncthreads();                        // only barrier in the kernel

    int lane = tid & 63, wv = tid >> 6;     // 4 waves: 2 wm x 2 wn
    int wm = wv >> 1, wn = wv & 1;
    int l15 = lane & 15, q = lane >> 4;

    const unsigned short* wgp = wb + (size_t)262144 * d_cumnc[g] + (size_t)ccol * 16384;
    int abase = l15 * 32 + q * 8;

    f32x4 acc[4][8];
#pragma unroll
    for (int mt = 0; mt < 4; ++mt)
#pragma unroll
        for (int nt = 0; nt < 8; ++nt) acc[mt][nt] = (f32x4)0.f;

    short8 a0[4], a1[4], b0[8], b1[8];

#define LOADAB(A, B, KK) { \
    int jjx = (KK) >> 2, ibx = (KK) & 3; \
    const unsigned short* tpx = wgp + (size_t)jjx * 16384; \
    int row0x = wn * 128 + l15 + jjx; \
    _Pragma("unroll") for (int mt = 0; mt < 4; ++mt) \
        A[mt] = *(const short8*)(tpx + ((wm * 4 + mt) * 4 + ibx) * 512 + abase); \
    _Pragma("unroll") for (int nt = 0; nt < 8; ++nt) { \
        int rowx = row0x + nt * 16; \
        B[nt] = *(const short8*)(&xs[rowx * 128 + (((ibx * 4 + q + rowx) & 15) << 3)]); \
    } }

#define FMAAB(A, B) { \
    _Pragma("unroll") for (int mt = 0; mt < 4; ++mt) \
    _Pragma("unroll") for (int nt = 0; nt < 8; ++nt) \
        acc[mt][nt] = __builtin_amdgcn_mfma_f32_16x16x32_bf16(A[mt], B[nt], acc[mt][nt], 0, 0, 0); }

    LOADAB(a0, b0, 0);
    for (int kk = 0; kk < 64; kk += 2) {
        LOADAB(a1, b1, kk + 1);
        FMAAB(a0, b0);
        if (kk + 2 < 64) LOADAB(a0, b0, kk + 2);
        FMAAB(a1, b1);
    }
#undef LOADAB
#undef FMAAB

    // epilogue into Y[p][g][b][o][t]
    float* yp = Y + (((size_t)p * NKv + g) * 2 + b) * 65536;
    int orow = wm * 64 + q * 4;
    int tcol = t0 + wn * 128 + l15;
    if (cid <= 3) {
#pragma unroll
        for (int mt = 0; mt < 4; ++mt)
#pragma unroll
            for (int nt = 0; nt < 8; ++nt)
#pragma unroll
                for (int rr = 0; rr < 4; ++rr)
                    yp[(size_t)(orow + mt * 16 + rr) * 512 + tcol + nt * 16] =
                        acc[mt][nt][rr];
    } else {
#pragma unroll
        for (int mt = 0; mt < 4; ++mt)
#pragma unroll
            for (int nt = 0; nt < 8; ++nt)
#pragma unroll
                for (int rr = 0; rr < 4; ++rr)
                    atomicAdd(&yp[(size_t)(orow + mt * 16 + rr) * 512 + tcol + nt * 16],
                              acc[mt][nt][rr]);
    }
}

// ---------------------------------------------------------------------------
// Masked-entry context, parallel v2: grid 256 = (bh x d-column). Each block:
// thread k computes S[k] = sum_g(K_p+bias), 9-step Hillis-Steele suffix scan
// in LDS, write ctx_masked[q,d] = 0.1 * sum_{k>q} S[k].
__global__ __launch_bounds__(512) void suffix_ctx(const float* __restrict__ Y,
                                                  const float* __restrict__ bconv,
                                                  float* __restrict__ out) {
    int blk = blockIdx.x;           // 256 = bh*16 + d
    int bh = blk >> 4, d = blk & 15;
    int b = bh >> 3, h = bh & 7;
    int k = threadIdx.x;            // 0..511
    int o = h * 16 + (k >> 5);
    int t = (k & 31) * 16 + d;

    float S = 0.f;
#pragma unroll
    for (int g = 0; g < NKv; ++g)
        S += Y[(((size_t)(NKv + g) * 2 + b) * 65536) + (size_t)o * 512 + t]
           + bconv[g * 128 + o];

    __shared__ float sc[512];
    sc[k] = S;
    __syncthreads();
    float v = S;
    for (int ofs = 1; ofs < 512; ofs <<= 1) {
        float add = (k + ofs < 512) ? sc[k + ofs] : 0.f;
        __syncthreads();
        v += add;
        sc[k] = v;
        __syncthreads();
    }
    // v = inclusive suffix sum; exclusive = v - S
    out[(((size_t)b * 8 + h) * 512 + k) * 16 + d] = 0.1f * (v - S);
}

// ---------------------------------------------------------------------------
// phase 2 (r11-verified f32 version): unmasked (k<=q) part, online softmax
// over g, 512 threads (32 q x 16 kl, 2 ki) -> 2 waves/SIMD.
__global__ __launch_bounds__(512) void attn_phase2(const float* __restrict__ Y,
                                                   const float* __restrict__ bconv,
                                                   float* __restrict__ out) {
    int blk = blockIdx.x;          // 256
    int half = blk & 1;
    int pr = blk >> 1;             // 128 pairs
    int bh = pr >> 3;
    int qp = pr & 7;
    int b = bh >> 3, h = bh & 7;

    int qtA = qp, qtB = 15 - qp;
    int u0 = half ? 8 : 0, u1 = half ? 17 : 8;

    __shared__ float Qs[2][NKv * 640];   // [X][g*640 + q*20 + d]
    __shared__ float Ks[NKv * 640];

    int tid = threadIdx.x;

#pragma unroll
    for (int X = 0; X < 2; ++X) {
        int o = h * 16 + (X ? qtB : qtA);
        for (int e = tid; e < NKv * 128; e += 512) {
            int g = e >> 7, c = e & 127;
            float4 v = *(const float4*)(Y + (((size_t)g * 2 + b) * 65536) +
                                        (size_t)o * 512 + c * 4);
            float bb = bconv[g * 128 + o];
            int qq2 = c >> 2, dd = c & 3;
            *(float4*)&Qs[X][g * 640 + qq2 * 20 + dd * 4] =
                make_float4(v.x + bb, v.y + bb, v.z + bb, v.w + bb);
        }
    }

    int q = (tid >> 4) & 31;
    int kl = tid & 15;
    float ctx[16];
#pragma unroll
    for (int d = 0; d < 16; ++d) ctx[d] = 0.f;
    int curX = (u0 <= qtA) ? 0 : 1;

    for (int u = u0; u < u1; ++u) {
        int X = (u <= qtA) ? 0 : 1;
        int qt = X ? qtB : qtA;
        int kt = X ? (u - qtA - 1) : u;

        if (X != curX) {
            int pqt = curX ? qtB : qtA;
#pragma unroll
            for (int d = 0; d < 16; ++d) {
                float v = ctx[d];
                v += __shfl_xor(v, 1);
                v += __shfl_xor(v, 2);
                v += __shfl_xor(v, 4);
                v += __shfl_xor(v, 8);
                if (kl == 0)
                    atomicAdd(&out[(((size_t)b * 8 + h) * 512 + pqt * 32 + q) * 16 + d], v);
                ctx[d] = 0.f;
            }
            curX = X;
        }

        __syncthreads();
        int o_k = h * 16 + kt;
        for (int e = tid; e < NKv * 128; e += 512) {
            int g = e >> 7, c = e & 127;
            float4 v = *(const float4*)(Y + (((size_t)(NKv + g) * 2 + b) * 65536) +
                                        (size_t)o_k * 512 + c * 4);
            float bb = bconv[g * 128 + o_k];
            int kk = c >> 2, dd = c & 3;
            *(float4*)&Ks[g * 640 + kk * 20 + dd * 4] =
                make_float4(v.x + bb, v.y + bb, v.z + bb, v.w + bb);
        }
        __syncthreads();

        int qg = qt * 32 + q;
        bool dg = (kt == qt);

        float m[2] = {-1e30f, -1e30f};
        float l[2] = {0.f, 0.f};
        float ca[2][16];
#pragma unroll
        for (int ki = 0; ki < 2; ++ki)
#pragma unroll
            for (int d = 0; d < 16; ++d) ca[ki][d] = 0.f;

        for (int g = 0; g < NKv; ++g) {
            const float* Qg = &Qs[X][g * 640 + q * 20];
            float4 qv0 = *(const float4*)(Qg);
            float4 qv1 = *(const float4*)(Qg + 4);
            float4 qv2 = *(const float4*)(Qg + 8);
            float4 qv3 = *(const float4*)(Qg + 12);
#pragma unroll
            for (int ki = 0; ki < 2; ++ki) {
                const float* Kg = &Ks[g * 640 + (ki * 16 + kl) * 20];
                float kv[16];
                *(float4*)&kv[0]  = *(const float4*)(Kg);
                *(float4*)&kv[4]  = *(const float4*)(Kg + 4);
                *(float4*)&kv[8]  = *(const float4*)(Kg + 8);
                *(float4*)&kv[12] = *(const float4*)(Kg + 12);
                float s = 0.f;
                s = fmaf(qv0.x, kv[0], s);  s = fmaf(qv0.y, kv[1], s);
                s = fmaf(qv0.z, kv[2], s);  s = fmaf(qv0.w, kv[3], s);
                s = fmaf(qv1.x, kv[4], s);  s = fmaf(qv1.y, kv[5], s);
                s = fmaf(qv1.z, kv[6], s);  s = fmaf(qv1.w, kv[7], s);
                s = fmaf(qv2.x, kv[8], s);  s = fmaf(qv2.y, kv[9], s);
                s = fmaf(qv2.z, kv[10], s); s = fmaf(qv2.w, kv[11], s);
                s = fmaf(qv3.x, kv[12], s); s = fmaf(qv3.y, kv[13], s);
                s = fmaf(qv3.z, kv[14], s); s = fmaf(qv3.w, kv[15], s);
                s *= 0.25f;
                float mn = fmaxf(m[ki], s);
                float sc = __expf(m[ki] - mn);
                float w  = __expf(s - mn);
                m[ki] = mn;
                l[ki] = l[ki] * sc + w;
#pragma unroll
                for (int d = 0; d < 16; ++d)
                    ca[ki][d] = fmaf(ca[ki][d], sc, w * kv[d]);
            }
        }

#pragma unroll
        for (int ki = 0; ki < 2; ++ki) {
            int kg = kt * 32 + ki * 16 + kl;
            float inv = (dg && kg > qg) ? 0.f : (1.f / l[ki]);
#pragma unroll
            for (int d = 0; d < 16; ++d) ctx[d] = fmaf(ca[ki][d], inv, ctx[d]);
        }
    }

    int pqt = curX ? qtB : qtA;
#pragma unroll
    for (int d = 0; d < 16; ++d) {
        float v = ctx[d];
        v += __shfl_xor(v, 1);
        v += __shfl_xor(v, 2);
        v += __shfl_xor(v, 4);
        v += __shfl_xor(v, 8);
        if (kl == 0)
            atomicAdd(&out[(((size_t)b * 8 + h) * 512 + pqt * 32 + q) * 16 + d], v);
    }
}

// ---------------------------------------------------------------------------
extern "C" void kernel_launch(void* const* d_in, const int* in_sizes, int n_in,
                              void* d_out, int out_size, void* d_ws, size_t ws_size,
                              hipStream_t stream) {
    const float* Q = (const float*)d_in[0];
    const float* K = (const float*)d_in[1];
    const float* W = (const float*)d_in[3];
    const float* bconv = (const float*)d_in[4];
    float* out = (float*)d_out;

    float* Y = (float*)d_ws;
    unsigned short* xr = (unsigned short*)((char*)d_ws + XR_OFF);
    unsigned short* wb = (unsigned short*)((char*)d_ws + WB_OFF);

    prep_repack<<<11392, 256, 0, stream>>>(Q, K, W, xr, wb, (float4*)Y, (float4*)out);

    conv_mfma<<<640, 256, 0, stream>>>(xr, wb, Y);

    suffix_ctx<<<256, 512, 0, stream>>>(Y, bconv, out);

    attn_phase2<<<256, 512, 0, stream>>>(Y, bconv, out);
}

// Round 17
// 186.716 us; speedup vs baseline: 1.4740x; 1.0675x over previous
//
#include <hip/hip_runtime.h>

// Problem constants
#define Bv 2
#define Hv 8
#define Lv 512
#define DKv 16
#define DMv 128          // H*DK
#define NKv 10
#define KSv 513

typedef __attribute__((ext_vector_type(8))) short short8;
typedef __attribute__((ext_vector_type(4))) float f32x4;

// chunk tables: nc_g = ceil((2^g+1)/16); chunks aligned to the END of the kernel
__device__ __constant__ int d_nc[10]     = {1,1,1,1,2,3,5,9,17,33};
__device__ __constant__ int d_cumnc[10]  = {0,1,2,3,4,6,9,14,23,40};
// total chunks = 73; cids 0-3 = g0-3 (sole writer), 4-8 = g4-5, 9-72 = g6-9

// ws layout (bytes):
//   Y    : f32 [2 p][10 g][2 b][128 o][512 t]          = 10,485,760 B
//   xr   : bf16 [2 p][2 b][512 t][128 i]               =    524,288 B
//   Wb   : bf16 [g][Tlocal][ A-frag layout ]           = 38,273,024 B
//   part : f32 [64 scid][8 yy][128 o][256 t]           = 67,108,864 B (optional)
#define Y_BYTES   (10485760)
#define XR_OFF    (Y_BYTES)
#define WB_OFF    (Y_BYTES + 524288)
#define PART_OFF  (WB_OFF + 38273024)
#define PART_BYTES (67108864)

__device__ inline unsigned short f2bf(float f) {
    unsigned u = __float_as_uint(f);
    unsigned r = (u + 0x7FFFu + ((u >> 16) & 1u)) >> 16;
    return (unsigned short)r;
}

// ---------------------------------------------------------------------------
// fused prep + repack_w (independent work, one launch):
//   blocks [0,9344): repack_w  — Wb[g][tap][Afrag(o,i)] <- bf16(W), 0-pad
//   blocks [9344,11392): prep  — zero Y g4..9, ones attn_out, repack_x
__global__ __launch_bounds__(256) void prep_repack(const float* __restrict__ Q,
                                                   const float* __restrict__ K,
                                                   const float* __restrict__ W,
                                                   unsigned short* __restrict__ xr,
                                                   unsigned short* __restrict__ wb,
                                                   float4* __restrict__ Y4,
                                                   float4* __restrict__ out4) {
    __shared__ float tile[128][17];       // [i][tap] (repack part only)
    int bid0 = blockIdx.x;
    int tid = threadIdx.x;

    if (bid0 < 9344) {
        int cid = bid0 >> 7;
        int o = bid0 & 127;
        int g, rem = cid;
#pragma unroll
        for (g = 0; g < 10; ++g) { int nc = d_nc[g]; if (rem < nc) break; rem -= nc; }
        int cl = rem;
        int w_g = d_nc[g] * 16;
        int ccol = w_g - 16 * (cl + 1);
        int wcolbase = 513 - w_g + ccol;      // absolute W col of chunk's tap 0

        const float* wsrc = W + (size_t)g * 16384 * 513 + (size_t)o * 128 * 513;
        int rr = tid >> 4, cc = tid & 15;
        int col = wcolbase + cc;
        for (int r = rr; r < 128; r += 16) {          // r = i
            float v = 0.f;
            if (col >= 0) v = wsrc[(size_t)r * 513 + col];
            tile[r][cc] = v;
        }
        __syncthreads();

        unsigned short* wdst = wb + (size_t)262144 * d_cumnc[g];
        int c2 = tid >> 4;          // tap 0..15
        int s  = tid & 15;          // ib(2) | qv(2)
        int ib = s >> 2, qv = s & 3;
        int i0 = ib * 32 + qv * 8;
        unsigned short pack[8];
#pragma unroll
        for (int e = 0; e < 8; ++e) pack[e] = f2bf(tile[i0 + e][c2]);
        size_t off = (size_t)(ccol + c2) * 16384 +
                     (((o >> 4) * 4 + ib) * 512 + (o & 15) * 32 + qv * 8);
        *(short8*)(wdst + off) = *(short8*)pack;      // 16B contiguous per thread
    } else {
        int stride = 2048 * 256;
        for (int i = (bid0 - 9344) * 256 + tid; i < 1507328; i += stride) {
            if (i < 196608) {
                Y4[131072 + i] = make_float4(0.f, 0.f, 0.f, 0.f);            // p0 g4..9
            } else if (i < 393216) {
                Y4[458752 + (i - 196608)] = make_float4(0.f, 0.f, 0.f, 0.f); // p1 g4..9
            } else if (i < 1441792) {
                out4[32768 + (i - 393216)] = make_float4(1.f, 1.f, 1.f, 1.f);
            } else {
                int idx = i - 1441792;               // 65536 items of 4 floats
                int flat = idx * 4;
                int p = flat >> 17;
                int off = flat & 131071;
                const float* src = p ? K : Q;
                float4 v = *(const float4*)(src + off);
                ushort4 o4;
                o4.x = f2bf(v.x); o4.y = f2bf(v.y); o4.z = f2bf(v.z); o4.w = f2bf(v.w);
                *(ushort4*)(xr + flat) = o4;
            }
        }
    }
}

// ---------------------------------------------------------------------------
// conv v9: v8 ping-pong pipeline; epilogue 3-way:
//   cid<=3 (g0-3, sole writer)      -> plain store to Y
//   cid 4..8 (g4-5) or no scratch   -> atomicAdd to Y
//   cid>=9 (g6-9), scratch enabled  -> plain store of partial to part[]
// Grid 640: j -> r=j&7 (XCD), yy=(j>>3)&7, cid=(j>>6)*8+r.
__global__ __launch_bounds__(256, 2) void conv_mfma(const unsigned short* __restrict__ xr,
                                                    const unsigned short* __restrict__ wb,
                                                    float* __restrict__ Y,
                                                    float* __restrict__ part,
                                                    int use_scratch) {
    int j = blockIdx.x;
    int r = j & 7, yy = (j >> 3) & 7, qq = j >> 6;
    int cid = qq * 8 + r;
    if (cid >= 73) return;
    int g, rem = cid;
#pragma unroll
    for (g = 0; g < 10; ++g) { int nc = d_nc[g]; if (rem < nc) break; rem -= nc; }
    int cl = rem;
    int w_g = d_nc[g] * 16;
    int ccol = w_g - 16 * (cl + 1);

    int p = yy >> 2, b = (yy >> 1) & 1, tt = yy & 1;
    int t0 = tt * 256;
    int pb = yy >> 1;

    int xbase = t0 + 1 - 16 * (cl + 1);    // x index of xs row 0
    if (xbase < -270) return;              // read window entirely < 0 (reduce knows)

    // xs: element (u,i) at u*128 + (((i>>3)+u)&15)*8 + (i&7); 272 rows
    __shared__ unsigned short xs[272 * 128];

    int tid = threadIdx.x;
    const unsigned short* xp = xr + (size_t)pb * 65536;
    for (int e = tid; e < 272 * 16; e += 256) {
        int u = e >> 4, ic = e & 15;
        int xi = xbase + u;
        short8 v = (short8)0;
        if (xi >= 0 && xi < 512) v = *(const short8*)(xp + (size_t)xi * 128 + ic * 8);
        *(short8*)(&xs[u * 128 + (((ic + u) & 15) << 3)]) = v;
    }
    __syncthreads();                        // only barrier in the kernel

    int lane = tid & 63, wv = tid >> 6;     // 4 waves: 2 wm x 2 wn
    int wm = wv >> 1, wn = wv & 1;
    int l15 = lane & 15, q = lane >> 4;

    const unsigned short* wgp = wb + (size_t)262144 * d_cumnc[g] + (size_t)ccol * 16384;
    int abase = l15 * 32 + q * 8;

    f32x4 acc[4][8];
#pragma unroll
    for (int mt = 0; mt < 4; ++mt)
#pragma unroll
        for (int nt = 0; nt < 8; ++nt) acc[mt][nt] = (f32x4)0.f;

    short8 a0[4], a1[4], b0[8], b1[8];

#define LOADAB(A, B, KK) { \
    int jjx = (KK) >> 2, ibx = (KK) & 3; \
    const unsigned short* tpx = wgp + (size_t)jjx * 16384; \
    int row0x = wn * 128 + l15 + jjx; \
    _Pragma("unroll") for (int mt = 0; mt < 4; ++mt) \
        A[mt] = *(const short8*)(tpx + ((wm * 4 + mt) * 4 + ibx) * 512 + abase); \
    _Pragma("unroll") for (int nt = 0; nt < 8; ++nt) { \
        int rowx = row0x + nt * 16; \
        B[nt] = *(const short8*)(&xs[rowx * 128 + (((ibx * 4 + q + rowx) & 15) << 3)]); \
    } }

#define FMAAB(A, B) { \
    _Pragma("unroll") for (int mt = 0; mt < 4; ++mt) \
    _Pragma("unroll") for (int nt = 0; nt < 8; ++nt) \
        acc[mt][nt] = __builtin_amdgcn_mfma_f32_16x16x32_bf16(A[mt], B[nt], acc[mt][nt], 0, 0, 0); }

    LOADAB(a0, b0, 0);
    for (int kk = 0; kk < 64; kk += 2) {
        LOADAB(a1, b1, kk + 1);
        FMAAB(a0, b0);
        if (kk + 2 < 64) LOADAB(a0, b0, kk + 2);
        FMAAB(a1, b1);
    }
#undef LOADAB
#undef FMAAB

    int orow = wm * 64 + q * 4;
    if (cid >= 9 && use_scratch) {
        // store partial [128 o][256 t] (reduce sums over this g's chunks)
        float* pp = part + ((size_t)(cid - 9) * 8 + yy) * 32768;
        int tloc = wn * 128 + l15;
#pragma unroll
        for (int mt = 0; mt < 4; ++mt)
#pragma unroll
            for (int nt = 0; nt < 8; ++nt)
#pragma unroll
                for (int rr = 0; rr < 4; ++rr)
                    pp[(size_t)(orow + mt * 16 + rr) * 256 + tloc + nt * 16] =
                        acc[mt][nt][rr];
        return;
    }

    float* yp = Y + (((size_t)p * NKv + g) * 2 + b) * 65536;
    int tcol = t0 + wn * 128 + l15;
    if (cid <= 3) {
#pragma unroll
        for (int mt = 0; mt < 4; ++mt)
#pragma unroll
            for (int nt = 0; nt < 8; ++nt)
#pragma unroll
                for (int rr = 0; rr < 4; ++rr)
                    yp[(size_t)(orow + mt * 16 + rr) * 512 + tcol + nt * 16] =
                        acc[mt][nt][rr];
    } else {
#pragma unroll
        for (int mt = 0; mt < 4; ++mt)
#pragma unroll
            for (int nt = 0; nt < 8; ++nt)
#pragma unroll
                for (int rr = 0; rr < 4; ++rr)
                    atomicAdd(&yp[(size_t)(orow + mt * 16 + rr) * 512 + tcol + nt * 16],
                              acc[mt][nt][rr]);
    }
}

// ---------------------------------------------------------------------------
// reduce partials for g6..9: Y[p][g][b][o][t] = sum_cl part[scid(g,cl)][yy][o][tloc]
// cl validity per tt replicates conv's skip rule: cl+1 <= (tt*256+271)>>4.
__global__ __launch_bounds__(256) void reduce_part(const float4* __restrict__ part4,
                                                   float4* __restrict__ Y4) {
    int idx = blockIdx.x * 256 + threadIdx.x;     // 262144 = 4g x 4pb x 128o x 128tc4
    if (idx >= 262144) return;
    int gg  = idx >> 16;            // 0..3 -> g = 6+gg
    int rem = idx & 65535;
    int pbi = rem >> 14;            // p*2+b
    int r2  = rem & 16383;
    int o   = r2 >> 7;              // 0..127
    int tc4 = r2 & 127;             // f4 col in 512-wide row
    int tt  = tc4 >> 6;
    int tl4 = tc4 & 63;

    const int cb[4]  = {0, 5, 14, 31};    // scid base for g6..9
    const int nch[4] = {5, 9, 17, 33};
    int n = nch[gg];
    int clmax = tt ? 32 : 16;             // max valid chunk count for this tt
    if (n > clmax) n = clmax;
    int base = cb[gg];
    int yy = pbi * 2 + tt;

    float4 s = make_float4(0.f, 0.f, 0.f, 0.f);
    for (int cl = 0; cl < n; ++cl) {
        float4 v = part4[((size_t)(base + cl) * 8 + yy) * 8192 + o * 64 + tl4];
        s.x += v.x; s.y += v.y; s.z += v.z; s.w += v.w;
    }
    int p = pbi >> 1, b = pbi & 1;
    Y4[(((size_t)p * NKv + 6 + gg) * 2 + b) * 16384 + o * 128 + tc4] = s;
}

// ---------------------------------------------------------------------------
// Masked-entry context, parallel v2: grid 256 = (bh x d-column). Each block:
// thread k computes S[k] = sum_g(K_p+bias), 9-step Hillis-Steele suffix scan
// in LDS, write ctx_masked[q,d] = 0.1 * sum_{k>q} S[k].
__global__ __launch_bounds__(512) void suffix_ctx(const float* __restrict__ Y,
                                                  const float* __restrict__ bconv,
                                                  float* __restrict__ out) {
    int blk = blockIdx.x;           // 256 = bh*16 + d
    int bh = blk >> 4, d = blk & 15;
    int b = bh >> 3, h = bh & 7;
    int k = threadIdx.x;            // 0..511
    int o = h * 16 + (k >> 5);
    int t = (k & 31) * 16 + d;

    float S = 0.f;
#pragma unroll
    for (int g = 0; g < NKv; ++g)
        S += Y[(((size_t)(NKv + g) * 2 + b) * 65536) + (size_t)o * 512 + t]
           + bconv[g * 128 + o];

    __shared__ float sc[512];
    sc[k] = S;
    __syncthreads();
    float v = S;
    for (int ofs = 1; ofs < 512; ofs <<= 1) {
        float add = (k + ofs < 512) ? sc[k + ofs] : 0.f;
        __syncthreads();
        v += add;
        sc[k] = v;
        __syncthreads();
    }
    // v = inclusive suffix sum; exclusive = v - S
    out[(((size_t)b * 8 + h) * 512 + k) * 16 + d] = 0.1f * (v - S);
}

// ---------------------------------------------------------------------------
// phase 2 (r11-verified f32 version): unmasked (k<=q) part, online softmax
// over g, 512 threads (32 q x 16 kl, 2 ki) -> 2 waves/SIMD.
__global__ __launch_bounds__(512) void attn_phase2(const float* __restrict__ Y,
                                                   const float* __restrict__ bconv,
                                                   float* __restrict__ out) {
    int blk = blockIdx.x;          // 256
    int half = blk & 1;
    int pr = blk >> 1;             // 128 pairs
    int bh = pr >> 3;
    int qp = pr & 7;
    int b = bh >> 3, h = bh & 7;

    int qtA = qp, qtB = 15 - qp;
    int u0 = half ? 8 : 0, u1 = half ? 17 : 8;

    __shared__ float Qs[2][NKv * 640];   // [X][g*640 + q*20 + d]
    __shared__ float Ks[NKv * 640];

    int tid = threadIdx.x;

#pragma unroll
    for (int X = 0; X < 2; ++X) {
        int o = h * 16 + (X ? qtB : qtA);
        for (int e = tid; e < NKv * 128; e += 512) {
            int g = e >> 7, c = e & 127;
            float4 v = *(const float4*)(Y + (((size_t)g * 2 + b) * 65536) +
                                        (size_t)o * 512 + c * 4);
            float bb = bconv[g * 128 + o];
            int qq2 = c >> 2, dd = c & 3;
            *(float4*)&Qs[X][g * 640 + qq2 * 20 + dd * 4] =
                make_float4(v.x + bb, v.y + bb, v.z + bb, v.w + bb);
        }
    }

    int q = (tid >> 4) & 31;
    int kl = tid & 15;
    float ctx[16];
#pragma unroll
    for (int d = 0; d < 16; ++d) ctx[d] = 0.f;
    int curX = (u0 <= qtA) ? 0 : 1;

    for (int u = u0; u < u1; ++u) {
        int X = (u <= qtA) ? 0 : 1;
        int qt = X ? qtB : qtA;
        int kt = X ? (u - qtA - 1) : u;

        if (X != curX) {
            int pqt = curX ? qtB : qtA;
#pragma unroll
            for (int d = 0; d < 16; ++d) {
                float v = ctx[d];
                v += __shfl_xor(v, 1);
                v += __shfl_xor(v, 2);
                v += __shfl_xor(v, 4);
                v += __shfl_xor(v, 8);
                if (kl == 0)
                    atomicAdd(&out[(((size_t)b * 8 + h) * 512 + pqt * 32 + q) * 16 + d], v);
                ctx[d] = 0.f;
            }
            curX = X;
        }

        __syncthreads();
        int o_k = h * 16 + kt;
        for (int e = tid; e < NKv * 128; e += 512) {
            int g = e >> 7, c = e & 127;
            float4 v = *(const float4*)(Y + (((size_t)(NKv + g) * 2 + b) * 65536) +
                                        (size_t)o_k * 512 + c * 4);
            float bb = bconv[g * 128 + o_k];
            int kk = c >> 2, dd = c & 3;
            *(float4*)&Ks[g * 640 + kk * 20 + dd * 4] =
                make_float4(v.x + bb, v.y + bb, v.z + bb, v.w + bb);
        }
        __syncthreads();

        int qg = qt * 32 + q;
        bool dg = (kt == qt);

        float m[2] = {-1e30f, -1e30f};
        float l[2] = {0.f, 0.f};
        float ca[2][16];
#pragma unroll
        for (int ki = 0; ki < 2; ++ki)
#pragma unroll
            for (int d = 0; d < 16; ++d) ca[ki][d] = 0.f;

        for (int g = 0; g < NKv; ++g) {
            const float* Qg = &Qs[X][g * 640 + q * 20];
            float4 qv0 = *(const float4*)(Qg);
            float4 qv1 = *(const float4*)(Qg + 4);
            float4 qv2 = *(const float4*)(Qg + 8);
            float4 qv3 = *(const float4*)(Qg + 12);
#pragma unroll
            for (int ki = 0; ki < 2; ++ki) {
                const float* Kg = &Ks[g * 640 + (ki * 16 + kl) * 20];
                float kv[16];
                *(float4*)&kv[0]  = *(const float4*)(Kg);
                *(float4*)&kv[4]  = *(const float4*)(Kg + 4);
                *(float4*)&kv[8]  = *(const float4*)(Kg + 8);
                *(float4*)&kv[12] = *(const float4*)(Kg + 12);
                float s = 0.f;
                s = fmaf(qv0.x, kv[0], s);  s = fmaf(qv0.y, kv[1], s);
                s = fmaf(qv0.z, kv[2], s);  s = fmaf(qv0.w, kv[3], s);
                s = fmaf(qv1.x, kv[4], s);  s = fmaf(qv1.y, kv[5], s);
                s = fmaf(qv1.z, kv[6], s);  s = fmaf(qv1.w, kv[7], s);
                s = fmaf(qv2.x, kv[8], s);  s = fmaf(qv2.y, kv[9], s);
                s = fmaf(qv2.z, kv[10], s); s = fmaf(qv2.w, kv[11], s);
                s = fmaf(qv3.x, kv[12], s); s = fmaf(qv3.y, kv[13], s);
                s = fmaf(qv3.z, kv[14], s); s = fmaf(qv3.w, kv[15], s);
                s *= 0.25f;
                float mn = fmaxf(m[ki], s);
                float sc = __expf(m[ki] - mn);
                float w  = __expf(s - mn);
                m[ki] = mn;
                l[ki] = l[ki] * sc + w;
#pragma unroll
                for (int d = 0; d < 16; ++d)
                    ca[ki][d] = fmaf(ca[ki][d], sc, w * kv[d]);
            }
        }

#pragma unroll
        for (int ki = 0; ki < 2; ++ki) {
            int kg = kt * 32 + ki * 16 + kl;
            float inv = (dg && kg > qg) ? 0.f : (1.f / l[ki]);
#pragma unroll
            for (int d = 0; d < 16; ++d) ctx[d] = fmaf(ca[ki][d], inv, ctx[d]);
        }
    }

    int pqt = curX ? qtB : qtA;
#pragma unroll
    for (int d = 0; d < 16; ++d) {
        float v = ctx[d];
        v += __shfl_xor(v, 1);
        v += __shfl_xor(v, 2);
        v += __shfl_xor(v, 4);
        v += __shfl_xor(v, 8);
        if (kl == 0)
            atomicAdd(&out[(((size_t)b * 8 + h) * 512 + pqt * 32 + q) * 16 + d], v);
    }
}

// ---------------------------------------------------------------------------
extern "C" void kernel_launch(void* const* d_in, const int* in_sizes, int n_in,
                              void* d_out, int out_size, void* d_ws, size_t ws_size,
                              hipStream_t stream) {
    const float* Q = (const float*)d_in[0];
    const float* K = (const float*)d_in[1];
    const float* W = (const float*)d_in[3];
    const float* bconv = (const float*)d_in[4];
    float* out = (float*)d_out;

    float* Y = (float*)d_ws;
    unsigned short* xr = (unsigned short*)((char*)d_ws + XR_OFF);
    unsigned short* wb = (unsigned short*)((char*)d_ws + WB_OFF);
    float* part = (float*)((char*)d_ws + PART_OFF);
    int use_scratch = (ws_size >= (size_t)PART_OFF + PART_BYTES) ? 1 : 0;

    prep_repack<<<11392, 256, 0, stream>>>(Q, K, W, xr, wb, (float4*)Y, (float4*)out);

    conv_mfma<<<640, 256, 0, stream>>>(xr, wb, Y, part, use_scratch);

    if (use_scratch)
        reduce_part<<<1024, 256, 0, stream>>>((const float4*)part, (float4*)Y);

    suffix_ctx<<<256, 512, 0, stream>>>(Y, bconv, out);

    attn_phase2<<<256, 512, 0, stream>>>(Y, bconv, out);
}

// Round 18
// 166.648 us; speedup vs baseline: 1.6515x; 1.1204x over previous
//
#include <hip/hip_runtime.h>

// Problem constants
#define Bv 2
#define Hv 8
#define Lv 512
#define DKv 16
#define DMv 128          // H*DK
#define NKv 10
#define KSv 513

typedef __attribute__((ext_vector_type(8))) short short8;
typedef __attribute__((ext_vector_type(4))) float f32x4;

// chunk tables: nc_g = ceil((2^g+1)/16); chunks aligned to the END of the kernel
__device__ __constant__ int d_nc[10]     = {1,1,1,1,2,3,5,9,17,33};
__device__ __constant__ int d_cumnc[10]  = {0,1,2,3,4,6,9,14,23,40};
// total chunks = 73; cids 0-3 = g0-3 (sole writer), 4-8 = g4-5, 9-72 = g6-9
// Skip analysis (xbase <= -271): cid 39 (g8 cl16) & cids 56..71 (g9 cl16..31)
// skip tt=0 (even yy); cid 72 (g9 cl32) skips both tt -> 508 real blocks.

// ws layout (bytes):
//   Y    : f32 [2 p][10 g][2 b][128 o][512 t]          = 10,485,760 B
//   xr   : bf16 [2 p][2 b][512 t][128 i]               =    524,288 B
//   Wb   : bf16 [g][Tlocal][ A-frag layout ]           = 38,273,024 B
//   part : f32 [64 scid][8 yy][128 o][256 t]           = 67,108,864 B (optional)
#define Y_BYTES   (10485760)
#define XR_OFF    (Y_BYTES)
#define WB_OFF    (Y_BYTES + 524288)
#define PART_OFF  (WB_OFF + 38273024)
#define PART_BYTES (67108864)

__device__ inline unsigned short f2bf(float f) {
    unsigned u = __float_as_uint(f);
    unsigned r = (u + 0x7FFFu + ((u >> 16) & 1u)) >> 16;
    return (unsigned short)r;
}

// ---------------------------------------------------------------------------
// fused prep + repack_w (independent work, one launch):
//   blocks [0,9344): repack_w  — Wb[g][tap][Afrag(o,i)] <- bf16(W), 0-pad
//   blocks [9344,11392): prep  — zero Y g4..9, ones attn_out, repack_x
__global__ __launch_bounds__(256) void prep_repack(const float* __restrict__ Q,
                                                   const float* __restrict__ K,
                                                   const float* __restrict__ W,
                                                   unsigned short* __restrict__ xr,
                                                   unsigned short* __restrict__ wb,
                                                   float4* __restrict__ Y4,
                                                   float4* __restrict__ out4) {
    __shared__ float tile[128][17];       // [i][tap] (repack part only)
    int bid0 = blockIdx.x;
    int tid = threadIdx.x;

    if (bid0 < 9344) {
        int cid = bid0 >> 7;
        int o = bid0 & 127;
        int g, rem = cid;
#pragma unroll
        for (g = 0; g < 10; ++g) { int nc = d_nc[g]; if (rem < nc) break; rem -= nc; }
        int cl = rem;
        int w_g = d_nc[g] * 16;
        int ccol = w_g - 16 * (cl + 1);
        int wcolbase = 513 - w_g + ccol;      // absolute W col of chunk's tap 0

        const float* wsrc = W + (size_t)g * 16384 * 513 + (size_t)o * 128 * 513;
        int rr = tid >> 4, cc = tid & 15;
        int col = wcolbase + cc;
        for (int r = rr; r < 128; r += 16) {          // r = i
            float v = 0.f;
            if (col >= 0) v = wsrc[(size_t)r * 513 + col];
            tile[r][cc] = v;
        }
        __syncthreads();

        unsigned short* wdst = wb + (size_t)262144 * d_cumnc[g];
        int c2 = tid >> 4;          // tap 0..15
        int s  = tid & 15;          // ib(2) | qv(2)
        int ib = s >> 2, qv = s & 3;
        int i0 = ib * 32 + qv * 8;
        unsigned short pack[8];
#pragma unroll
        for (int e = 0; e < 8; ++e) pack[e] = f2bf(tile[i0 + e][c2]);
        size_t off = (size_t)(ccol + c2) * 16384 +
                     (((o >> 4) * 4 + ib) * 512 + (o & 15) * 32 + qv * 8);
        *(short8*)(wdst + off) = *(short8*)pack;      // 16B contiguous per thread
    } else {
        int stride = 2048 * 256;
        for (int i = (bid0 - 9344) * 256 + tid; i < 1507328; i += stride) {
            if (i < 196608) {
                Y4[131072 + i] = make_float4(0.f, 0.f, 0.f, 0.f);            // p0 g4..9
            } else if (i < 393216) {
                Y4[458752 + (i - 196608)] = make_float4(0.f, 0.f, 0.f, 0.f); // p1 g4..9
            } else if (i < 1441792) {
                out4[32768 + (i - 393216)] = make_float4(1.f, 1.f, 1.f, 1.f);
            } else {
                int idx = i - 1441792;               // 65536 items of 4 floats
                int flat = idx * 4;
                int p = flat >> 17;
                int off = flat & 131071;
                const float* src = p ? K : Q;
                float4 v = *(const float4*)(src + off);
                ushort4 o4;
                o4.x = f2bf(v.x); o4.y = f2bf(v.y); o4.z = f2bf(v.z); o4.w = f2bf(v.w);
                *(ushort4*)(xr + flat) = o4;
            }
        }
    }
}

// ---------------------------------------------------------------------------
// conv v10: v9 pipeline + COMPACT dispatch. Grid 512 (one co-resident round
// at 2 blocks/CU): j=(idx,r) walks to the idx-th REAL (cid,yy) among cids
// congruent r (mod 8) — skipped (cid,yy) combos never get a block. Per-XCD
// real counts {64x7, 60}; XCD locality preserved (cid = r mod 8).
// Epilogue 3-way: cid<=3 store; cid 4..8 (or no scratch) atomic; else partial.
__global__ __launch_bounds__(256, 2) void conv_mfma(const unsigned short* __restrict__ xr,
                                                    const unsigned short* __restrict__ wb,
                                                    float* __restrict__ Y,
                                                    float* __restrict__ part,
                                                    int use_scratch) {
    int j = blockIdx.x;
    int cid = -1, yy = 0;
    {
        int idx = j >> 3, r = j & 7;
        for (int c = r; c < 73; c += 8) {
            int cnt = (c == 72) ? 0 : ((c == 39 || (c >= 56 && c <= 71)) ? 4 : 8);
            if (idx < cnt) { cid = c; yy = (cnt == 8) ? idx : (2 * idx + 1); break; }
            idx -= cnt;
        }
        if (cid < 0) return;
    }
    int g, rem = cid;
#pragma unroll
    for (g = 0; g < 10; ++g) { int nc = d_nc[g]; if (rem < nc) break; rem -= nc; }
    int cl = rem;
    int w_g = d_nc[g] * 16;
    int ccol = w_g - 16 * (cl + 1);

    int p = yy >> 2, b = (yy >> 1) & 1, tt = yy & 1;
    int t0 = tt * 256;
    int pb = yy >> 1;

    int xbase = t0 + 1 - 16 * (cl + 1);    // x index of xs row 0
    if (xbase < -270) return;              // safety net (never true w/ table)

    // xs: element (u,i) at u*128 + (((i>>3)+u)&15)*8 + (i&7); 272 rows
    __shared__ unsigned short xs[272 * 128];

    int tid = threadIdx.x;
    const unsigned short* xp = xr + (size_t)pb * 65536;
    for (int e = tid; e < 272 * 16; e += 256) {
        int u = e >> 4, ic = e & 15;
        int xi = xbase + u;
        short8 v = (short8)0;
        if (xi >= 0 && xi < 512) v = *(const short8*)(xp + (size_t)xi * 128 + ic * 8);
        *(short8*)(&xs[u * 128 + (((ic + u) & 15) << 3)]) = v;
    }
    __syncthreads();                        // only barrier in the kernel

    int lane = tid & 63, wv = tid >> 6;     // 4 waves: 2 wm x 2 wn
    int wm = wv >> 1, wn = wv & 1;
    int l15 = lane & 15, q = lane >> 4;

    const unsigned short* wgp = wb + (size_t)262144 * d_cumnc[g] + (size_t)ccol * 16384;
    int abase = l15 * 32 + q * 8;

    f32x4 acc[4][8];
#pragma unroll
    for (int mt = 0; mt < 4; ++mt)
#pragma unroll
        for (int nt = 0; nt < 8; ++nt) acc[mt][nt] = (f32x4)0.f;

    short8 a0[4], a1[4], b0[8], b1[8];

#define LOADAB(A, B, KK) { \
    int jjx = (KK) >> 2, ibx = (KK) & 3; \
    const unsigned short* tpx = wgp + (size_t)jjx * 16384; \
    int row0x = wn * 128 + l15 + jjx; \
    _Pragma("unroll") for (int mt = 0; mt < 4; ++mt) \
        A[mt] = *(const short8*)(tpx + ((wm * 4 + mt) * 4 + ibx) * 512 + abase); \
    _Pragma("unroll") for (int nt = 0; nt < 8; ++nt) { \
        int rowx = row0x + nt * 16; \
        B[nt] = *(const short8*)(&xs[rowx * 128 + (((ibx * 4 + q + rowx) & 15) << 3)]); \
    } }

#define FMAAB(A, B) { \
    _Pragma("unroll") for (int mt = 0; mt < 4; ++mt) \
    _Pragma("unroll") for (int nt = 0; nt < 8; ++nt) \
        acc[mt][nt] = __builtin_amdgcn_mfma_f32_16x16x32_bf16(A[mt], B[nt], acc[mt][nt], 0, 0, 0); }

    LOADAB(a0, b0, 0);
    for (int kk = 0; kk < 64; kk += 2) {
        LOADAB(a1, b1, kk + 1);
        FMAAB(a0, b0);
        if (kk + 2 < 64) LOADAB(a0, b0, kk + 2);
        FMAAB(a1, b1);
    }
#undef LOADAB
#undef FMAAB

    int orow = wm * 64 + q * 4;
    if (cid >= 9 && use_scratch) {
        // store partial [128 o][256 t] (reduce sums over this g's chunks)
        float* pp = part + ((size_t)(cid - 9) * 8 + yy) * 32768;
        int tloc = wn * 128 + l15;
#pragma unroll
        for (int mt = 0; mt < 4; ++mt)
#pragma unroll
            for (int nt = 0; nt < 8; ++nt)
#pragma unroll
                for (int rr = 0; rr < 4; ++rr)
                    pp[(size_t)(orow + mt * 16 + rr) * 256 + tloc + nt * 16] =
                        acc[mt][nt][rr];
        return;
    }

    float* yp = Y + (((size_t)p * NKv + g) * 2 + b) * 65536;
    int tcol = t0 + wn * 128 + l15;
    if (cid <= 3) {
#pragma unroll
        for (int mt = 0; mt < 4; ++mt)
#pragma unroll
            for (int nt = 0; nt < 8; ++nt)
#pragma unroll
                for (int rr = 0; rr < 4; ++rr)
                    yp[(size_t)(orow + mt * 16 + rr) * 512 + tcol + nt * 16] =
                        acc[mt][nt][rr];
    } else {
#pragma unroll
        for (int mt = 0; mt < 4; ++mt)
#pragma unroll
            for (int nt = 0; nt < 8; ++nt)
#pragma unroll
                for (int rr = 0; rr < 4; ++rr)
                    atomicAdd(&yp[(size_t)(orow + mt * 16 + rr) * 512 + tcol + nt * 16],
                              acc[mt][nt][rr]);
    }
}

// ---------------------------------------------------------------------------
// reduce partials for g6..9: Y[p][g][b][o][t] = sum_cl part[scid(g,cl)][yy][o][tloc]
// cl validity per tt replicates conv's skip rule.
__global__ __launch_bounds__(256) void reduce_part(const float4* __restrict__ part4,
                                                   float4* __restrict__ Y4) {
    int idx = blockIdx.x * 256 + threadIdx.x;     // 262144 = 4g x 4pb x 128o x 128tc4
    if (idx >= 262144) return;
    int gg  = idx >> 16;            // 0..3 -> g = 6+gg
    int rem = idx & 65535;
    int pbi = rem >> 14;            // p*2+b
    int r2  = rem & 16383;
    int o   = r2 >> 7;              // 0..127
    int tc4 = r2 & 127;             // f4 col in 512-wide row
    int tt  = tc4 >> 6;
    int tl4 = tc4 & 63;

    const int cb[4]  = {0, 5, 14, 31};    // scid base for g6..9
    const int nch[4] = {5, 9, 17, 33};
    int n = nch[gg];
    int clmax = tt ? 32 : 16;             // max valid chunk count for this tt
    if (n > clmax) n = clmax;
    int base = cb[gg];
    int yy = pbi * 2 + tt;

    float4 s = make_float4(0.f, 0.f, 0.f, 0.f);
    for (int cl = 0; cl < n; ++cl) {
        float4 v = part4[((size_t)(base + cl) * 8 + yy) * 8192 + o * 64 + tl4];
        s.x += v.x; s.y += v.y; s.z += v.z; s.w += v.w;
    }
    int p = pbi >> 1, b = pbi & 1;
    Y4[(((size_t)p * NKv + 6 + gg) * 2 + b) * 16384 + o * 128 + tc4] = s;
}

// ---------------------------------------------------------------------------
// Masked-entry context, parallel v2: grid 256 = (bh x d-column). Each block:
// thread k computes S[k] = sum_g(K_p+bias), 9-step Hillis-Steele suffix scan
// in LDS, write ctx_masked[q,d] = 0.1 * sum_{k>q} S[k].
__global__ __launch_bounds__(512) void suffix_ctx(const float* __restrict__ Y,
                                                  const float* __restrict__ bconv,
                                                  float* __restrict__ out) {
    int blk = blockIdx.x;           // 256 = bh*16 + d
    int bh = blk >> 4, d = blk & 15;
    int b = bh >> 3, h = bh & 7;
    int k = threadIdx.x;            // 0..511
    int o = h * 16 + (k >> 5);
    int t = (k & 31) * 16 + d;

    float S = 0.f;
#pragma unroll
    for (int g = 0; g < NKv; ++g)
        S += Y[(((size_t)(NKv + g) * 2 + b) * 65536) + (size_t)o * 512 + t]
           + bconv[g * 128 + o];

    __shared__ float sc[512];
    sc[k] = S;
    __syncthreads();
    float v = S;
    for (int ofs = 1; ofs < 512; ofs <<= 1) {
        float add = (k + ofs < 512) ? sc[k + ofs] : 0.f;
        __syncthreads();
        v += add;
        sc[k] = v;
        __syncthreads();
    }
    // v = inclusive suffix sum; exclusive = v - S
    out[(((size_t)b * 8 + h) * 512 + k) * 16 + d] = 0.1f * (v - S);
}

// ---------------------------------------------------------------------------
// phase 2 (r11-verified f32 version): unmasked (k<=q) part, online softmax
// over g, 512 threads (32 q x 16 kl, 2 ki) -> 2 waves/SIMD.
__global__ __launch_bounds__(512) void attn_phase2(const float* __restrict__ Y,
                                                   const float* __restrict__ bconv,
                                                   float* __restrict__ out) {
    int blk = blockIdx.x;          // 256
    int half = blk & 1;
    int pr = blk >> 1;             // 128 pairs
    int bh = pr >> 3;
    int qp = pr & 7;
    int b = bh >> 3, h = bh & 7;

    int qtA = qp, qtB = 15 - qp;
    int u0 = half ? 8 : 0, u1 = half ? 17 : 8;

    __shared__ float Qs[2][NKv * 640];   // [X][g*640 + q*20 + d]
    __shared__ float Ks[NKv * 640];

    int tid = threadIdx.x;

#pragma unroll
    for (int X = 0; X < 2; ++X) {
        int o = h * 16 + (X ? qtB : qtA);
        for (int e = tid; e < NKv * 128; e += 512) {
            int g = e >> 7, c = e & 127;
            float4 v = *(const float4*)(Y + (((size_t)g * 2 + b) * 65536) +
                                        (size_t)o * 512 + c * 4);
            float bb = bconv[g * 128 + o];
            int qq2 = c >> 2, dd = c & 3;
            *(float4*)&Qs[X][g * 640 + qq2 * 20 + dd * 4] =
                make_float4(v.x + bb, v.y + bb, v.z + bb, v.w + bb);
        }
    }

    int q = (tid >> 4) & 31;
    int kl = tid & 15;
    float ctx[16];
#pragma unroll
    for (int d = 0; d < 16; ++d) ctx[d] = 0.f;
    int curX = (u0 <= qtA) ? 0 : 1;

    for (int u = u0; u < u1; ++u) {
        int X = (u <= qtA) ? 0 : 1;
        int qt = X ? qtB : qtA;
        int kt = X ? (u - qtA - 1) : u;

        if (X != curX) {
            int pqt = curX ? qtB : qtA;
#pragma unroll
            for (int d = 0; d < 16; ++d) {
                float v = ctx[d];
                v += __shfl_xor(v, 1);
                v += __shfl_xor(v, 2);
                v += __shfl_xor(v, 4);
                v += __shfl_xor(v, 8);
                if (kl == 0)
                    atomicAdd(&out[(((size_t)b * 8 + h) * 512 + pqt * 32 + q) * 16 + d], v);
                ctx[d] = 0.f;
            }
            curX = X;
        }

        __syncthreads();
        int o_k = h * 16 + kt;
        for (int e = tid; e < NKv * 128; e += 512) {
            int g = e >> 7, c = e & 127;
            float4 v = *(const float4*)(Y + (((size_t)(NKv + g) * 2 + b) * 65536) +
                                        (size_t)o_k * 512 + c * 4);
            float bb = bconv[g * 128 + o_k];
            int kk = c >> 2, dd = c & 3;
            *(float4*)&Ks[g * 640 + kk * 20 + dd * 4] =
                make_float4(v.x + bb, v.y + bb, v.z + bb, v.w + bb);
        }
        __syncthreads();

        int qg = qt * 32 + q;
        bool dg = (kt == qt);

        float m[2] = {-1e30f, -1e30f};
        float l[2] = {0.f, 0.f};
        float ca[2][16];
#pragma unroll
        for (int ki = 0; ki < 2; ++ki)
#pragma unroll
            for (int d = 0; d < 16; ++d) ca[ki][d] = 0.f;

        for (int g = 0; g < NKv; ++g) {
            const float* Qg = &Qs[X][g * 640 + q * 20];
            float4 qv0 = *(const float4*)(Qg);
            float4 qv1 = *(const float4*)(Qg + 4);
            float4 qv2 = *(const float4*)(Qg + 8);
            float4 qv3 = *(const float4*)(Qg + 12);
#pragma unroll
            for (int ki = 0; ki < 2; ++ki) {
                const float* Kg = &Ks[g * 640 + (ki * 16 + kl) * 20];
                float kv[16];
                *(float4*)&kv[0]  = *(const float4*)(Kg);
                *(float4*)&kv[4]  = *(const float4*)(Kg + 4);
                *(float4*)&kv[8]  = *(const float4*)(Kg + 8);
                *(float4*)&kv[12] = *(const float4*)(Kg + 12);
                float s = 0.f;
                s = fmaf(qv0.x, kv[0], s);  s = fmaf(qv0.y, kv[1], s);
                s = fmaf(qv0.z, kv[2], s);  s = fmaf(qv0.w, kv[3], s);
                s = fmaf(qv1.x, kv[4], s);  s = fmaf(qv1.y, kv[5], s);
                s = fmaf(qv1.z, kv[6], s);  s = fmaf(qv1.w, kv[7], s);
                s = fmaf(qv2.x, kv[8], s);  s = fmaf(qv2.y, kv[9], s);
                s = fmaf(qv2.z, kv[10], s); s = fmaf(qv2.w, kv[11], s);
                s = fmaf(qv3.x, kv[12], s); s = fmaf(qv3.y, kv[13], s);
                s = fmaf(qv3.z, kv[14], s); s = fmaf(qv3.w, kv[15], s);
                s *= 0.25f;
                float mn = fmaxf(m[ki], s);
                float sc = __expf(m[ki] - mn);
                float w  = __expf(s - mn);
                m[ki] = mn;
                l[ki] = l[ki] * sc + w;
#pragma unroll
                for (int d = 0; d < 16; ++d)
                    ca[ki][d] = fmaf(ca[ki][d], sc, w * kv[d]);
            }
        }

#pragma unroll
        for (int ki = 0; ki < 2; ++ki) {
            int kg = kt * 32 + ki * 16 + kl;
            float inv = (dg && kg > qg) ? 0.f : (1.f / l[ki]);
#pragma unroll
            for (int d = 0; d < 16; ++d) ctx[d] = fmaf(ca[ki][d], inv, ctx[d]);
        }
    }

    int pqt = curX ? qtB : qtA;
#pragma unroll
    for (int d = 0; d < 16; ++d) {
        float v = ctx[d];
        v += __shfl_xor(v, 1);
        v += __shfl_xor(v, 2);
        v += __shfl_xor(v, 4);
        v += __shfl_xor(v, 8);
        if (kl == 0)
            atomicAdd(&out[(((size_t)b * 8 + h) * 512 + pqt * 32 + q) * 16 + d], v);
    }
}

// ---------------------------------------------------------------------------
extern "C" void kernel_launch(void* const* d_in, const int* in_sizes, int n_in,
                              void* d_out, int out_size, void* d_ws, size_t ws_size,
                              hipStream_t stream) {
    const float* Q = (const float*)d_in[0];
    const float* K = (const float*)d_in[1];
    const float* W = (const float*)d_in[3];
    const float* bconv = (const float*)d_in[4];
    float* out = (float*)d_out;

    float* Y = (float*)d_ws;
    unsigned short* xr = (unsigned short*)((char*)d_ws + XR_OFF);
    unsigned short* wb = (unsigned short*)((char*)d_ws + WB_OFF);
    float* part = (float*)((char*)d_ws + PART_OFF);
    int use_scratch = (ws_size >= (size_t)PART_OFF + PART_BYTES) ? 1 : 0;

    prep_repack<<<11392, 256, 0, stream>>>(Q, K, W, xr, wb, (float4*)Y, (float4*)out);

    conv_mfma<<<512, 256, 0, stream>>>(xr, wb, Y, part, use_scratch);

    if (use_scratch)
        reduce_part<<<1024, 256, 0, stream>>>((const float4*)part, (float4*)Y);

    suffix_ctx<<<256, 512, 0, stream>>>(Y, bconv, out);

    attn_phase2<<<256, 512, 0, stream>>>(Y, bconv, out);
}